// Round 1
// baseline (3218.575 us; speedup 1.0000x reference)
//
#include <hip/hip_runtime.h>

// GraphSAGE block: mean-aggregate -> SAGEConv (lin_l(agg)+b + lin_r(x)) -> LayerNorm -> ReLU
// N=100000, E=1600000, D_IN=D_OUT=128

#define D 128

// ---------------- Kernel 1: zero agg (=d_out) and deg ----------------
__global__ void zero_kernel(float* __restrict__ agg, float* __restrict__ deg, int n_nodes) {
    int total = n_nodes * D + n_nodes;
    for (int i = blockIdx.x * blockDim.x + threadIdx.x; i < total;
         i += gridDim.x * blockDim.x) {
        if (i < n_nodes * D) agg[i] = 0.0f;
        else                 deg[i - n_nodes * D] = 0.0f;
    }
}

// ---------------- Kernel 2: edge scatter (atomic) ----------------
// 32 threads per edge; thread j handles features [4j, 4j+4)
__global__ void scatter_kernel(const float* __restrict__ x,
                               const int* __restrict__ ei,
                               float* __restrict__ agg,
                               float* __restrict__ deg,
                               int n_edges) {
    long long total = (long long)n_edges * 32;
    for (long long idx = blockIdx.x * (long long)blockDim.x + threadIdx.x;
         idx < total;
         idx += (long long)gridDim.x * blockDim.x) {
        int e = (int)(idx >> 5);
        int j = (int)(idx & 31);
        int src = ei[e];
        int dst = ei[n_edges + e];
        float4 v = reinterpret_cast<const float4*>(x)[(long long)src * 32 + j];
        float* a = agg + (long long)dst * D + j * 4;
        atomicAdd(a + 0, v.x);
        atomicAdd(a + 1, v.y);
        atomicAdd(a + 2, v.z);
        atomicAdd(a + 3, v.w);
        if (j == 0) atomicAdd(deg + dst, 1.0f);
    }
}

// ---------------- Kernel 3: fused SAGEConv + LayerNorm + ReLU ----------------
// One wave (64 lanes) per node; lane l computes output features l and l+64.
// W_l^T, W_r^T staged in LDS with stride 129 (conflict-free: bank=(k+d)%32).
__global__ __launch_bounds__(256) void sage_kernel(
        const float* __restrict__ x,
        const float* __restrict__ agg_in,   // aliases d_out (read row n before writing it)
        const float* __restrict__ deg,
        const float* __restrict__ Wl,
        const float* __restrict__ bl,
        const float* __restrict__ Wr,
        const float* __restrict__ gamma,
        const float* __restrict__ beta,
        float* __restrict__ out,
        int n_nodes) {
    __shared__ float wlt[128 * 129];
    __shared__ float wrt[128 * 129];
    __shared__ float rows[4][256];

    int tid = threadIdx.x;
    // stage W transposed: wlt[k*129+d] = Wl[d*128+k]
    for (int i = tid; i < 128 * 128; i += 256) {
        int d = i >> 7;
        int k = i & 127;
        wlt[k * 129 + d] = Wl[i];
        wrt[k * 129 + d] = Wr[i];
    }
    __syncthreads();

    int wave = tid >> 6;
    int lane = tid & 63;
    int gwave = blockIdx.x * 4 + wave;
    int nwaves = gridDim.x * 4;
    float* row = rows[wave];

    int d0 = lane, d1 = lane + 64;
    float bl0 = bl[d0], bl1 = bl[d1];
    float g0 = gamma[d0], g1 = gamma[d1];
    float be0 = beta[d0], be1 = beta[d1];

    for (int n = gwave; n < n_nodes; n += nwaves) {
        float inv = 1.0f / fmaxf(deg[n], 1.0f);
        long long base = (long long)n * D;
        // stage (agg/deg) row and x row into per-wave LDS
        row[lane]       = agg_in[base + lane] * inv;
        row[lane + 64]  = agg_in[base + lane + 64] * inv;
        row[lane + 128] = x[base + lane];
        row[lane + 192] = x[base + lane + 64];

        float acc0 = bl0, acc1 = bl1;
        #pragma unroll 4
        for (int k = 0; k < 128; ++k) {
            float a  = row[k];
            float xv = row[128 + k];
            acc0 += a * wlt[k * 129 + d0];
            acc1 += a * wlt[k * 129 + d1];
            acc0 += xv * wrt[k * 129 + d0];
            acc1 += xv * wrt[k * 129 + d1];
        }

        // LayerNorm over 128 features (2 per lane, butterfly reduce across 64 lanes)
        float s  = acc0 + acc1;
        float sq = acc0 * acc0 + acc1 * acc1;
        #pragma unroll
        for (int off = 32; off >= 1; off >>= 1) {
            s  += __shfl_xor(s, off, 64);
            sq += __shfl_xor(sq, off, 64);
        }
        float mu   = s * (1.0f / 128.0f);
        float var  = sq * (1.0f / 128.0f) - mu * mu;
        float rstd = rsqrtf(var + 1e-5f);
        float o0 = (acc0 - mu) * rstd * g0 + be0;
        float o1 = (acc1 - mu) * rstd * g1 + be1;
        out[base + d0] = fmaxf(o0, 0.0f);
        out[base + d1] = fmaxf(o1, 0.0f);
    }
}

extern "C" void kernel_launch(void* const* d_in, const int* in_sizes, int n_in,
                              void* d_out, int out_size, void* d_ws, size_t ws_size,
                              hipStream_t stream) {
    const float* x     = (const float*)d_in[0];
    const int*   ei    = (const int*)d_in[1];
    const float* Wl    = (const float*)d_in[2];
    const float* bl    = (const float*)d_in[3];
    const float* Wr    = (const float*)d_in[4];
    const float* gamma = (const float*)d_in[5];
    const float* beta  = (const float*)d_in[6];

    int n_nodes = in_sizes[0] / D;
    int n_edges = in_sizes[1] / 2;

    float* agg = (float*)d_out;          // reuse d_out as the aggregation buffer
    float* deg = (float*)d_ws;           // N floats of scratch

    zero_kernel<<<2048, 256, 0, stream>>>(agg, deg, n_nodes);
    scatter_kernel<<<2048, 256, 0, stream>>>(x, ei, agg, deg, n_edges);
    sage_kernel<<<256, 256, 0, stream>>>(x, agg, deg, Wl, bl, Wr, gamma, beta,
                                         (float*)d_out, n_nodes);
}

// Round 2
// 748.311 us; speedup vs baseline: 4.3011x; 4.3011x over previous
//
#include <hip/hip_runtime.h>

// GraphSAGE block: CSR-gather mean -> SAGEConv (lin_l(agg)+b + lin_r(x)) -> LayerNorm -> ReLU
// N=100000, E=1600000, D_IN=D_OUT=128

#define D 128

// ---------------- zero int array ----------------
__global__ void zero_int(int* __restrict__ p, int n) {
    for (int i = blockIdx.x * blockDim.x + threadIdx.x; i < n;
         i += gridDim.x * blockDim.x) p[i] = 0;
}

// ---------------- count degrees (int atomics, 1.6M on 100k counters) ----------------
__global__ void count_kernel(const int* __restrict__ ei, int* __restrict__ deg, int n_edges) {
    for (int e = blockIdx.x * blockDim.x + threadIdx.x; e < n_edges;
         e += gridDim.x * blockDim.x)
        atomicAdd(&deg[ei[n_edges + e]], 1);
}

// ---------------- exclusive prefix sum, single block, 4 elems/thread ----------------
__global__ __launch_bounds__(1024) void scan_kernel(const int* __restrict__ deg,
                                                    int* __restrict__ offs,
                                                    int* __restrict__ cursor, int n) {
    __shared__ int tmp[1024];
    __shared__ int carry;
    int tid = threadIdx.x;
    if (tid == 0) carry = 0;
    __syncthreads();
    for (int base = 0; base < n; base += 4096) {
        int i0 = base + tid * 4;
        int v[4], p[4], s = 0;
        #pragma unroll
        for (int j = 0; j < 4; ++j) {
            v[j] = (i0 + j < n) ? deg[i0 + j] : 0;
            p[j] = s; s += v[j];
        }
        tmp[tid] = s;
        __syncthreads();
        for (int off = 1; off < 1024; off <<= 1) {
            int t = (tid >= off) ? tmp[tid - off] : 0;
            __syncthreads();
            tmp[tid] += t;
            __syncthreads();
        }
        int excl = tmp[tid] - s;
        int ctot = tmp[1023];
        int c = carry;
        #pragma unroll
        for (int j = 0; j < 4; ++j)
            if (i0 + j < n) { int o = c + excl + p[j]; offs[i0 + j] = o; cursor[i0 + j] = o; }
        __syncthreads();
        if (tid == 0) carry += ctot;
        __syncthreads();
    }
    if (tid == 0) offs[n] = carry;
}

// ---------------- fill CSR neighbor lists ----------------
__global__ void fill_kernel(const int* __restrict__ ei, int* __restrict__ cursor,
                            int* __restrict__ csr, int n_edges) {
    for (int e = blockIdx.x * blockDim.x + threadIdx.x; e < n_edges;
         e += gridDim.x * blockDim.x) {
        int src = ei[e];
        int dst = ei[n_edges + e];
        int pos = atomicAdd(&cursor[dst], 1);
        csr[pos] = src;
    }
}

// ---------------- per-node gather + mean (wave per node, float2 lanes) ----------------
__global__ void gather_kernel(const float* __restrict__ x,
                              const int* __restrict__ offs,
                              const int* __restrict__ csr,
                              float* __restrict__ agg, int n_nodes) {
    int lane = threadIdx.x & 63;
    int gw = (blockIdx.x * blockDim.x + threadIdx.x) >> 6;
    int nw = (gridDim.x * blockDim.x) >> 6;
    for (int node = gw; node < n_nodes; node += nw) {
        int o0 = offs[node], o1 = offs[node + 1];
        float ax = 0.0f, ay = 0.0f;
        for (int i = o0; i < o1; ++i) {
            int src = csr[i];
            float2 v = reinterpret_cast<const float2*>(x)[src * 64 + lane];
            ax += v.x; ay += v.y;
        }
        float inv = 1.0f / fmaxf((float)(o1 - o0), 1.0f);
        float2 r; r.x = ax * inv; r.y = ay * inv;
        reinterpret_cast<float2*>(agg)[node * 64 + lane] = r;
    }
}

// ---------------- old-path atomic scatter (fallback if ws too small) ----------------
__global__ void zero_f(float* __restrict__ a, float* __restrict__ dg, int n_nodes) {
    int total = n_nodes * D + n_nodes;
    for (int i = blockIdx.x * blockDim.x + threadIdx.x; i < total;
         i += gridDim.x * blockDim.x) {
        if (i < n_nodes * D) a[i] = 0.0f;
        else                 dg[i - n_nodes * D] = 0.0f;
    }
}
__global__ void scatter_kernel(const float* __restrict__ x, const int* __restrict__ ei,
                               float* __restrict__ agg, float* __restrict__ deg, int n_edges) {
    long long total = (long long)n_edges * 32;
    for (long long idx = blockIdx.x * (long long)blockDim.x + threadIdx.x; idx < total;
         idx += (long long)gridDim.x * blockDim.x) {
        int e = (int)(idx >> 5);
        int j = (int)(idx & 31);
        int src = ei[e];
        int dst = ei[n_edges + e];
        float4 v = reinterpret_cast<const float4*>(x)[(long long)src * 32 + j];
        float* a = agg + (long long)dst * D + j * 4;
        atomicAdd(a + 0, v.x); atomicAdd(a + 1, v.y);
        atomicAdd(a + 2, v.z); atomicAdd(a + 3, v.w);
        if (j == 0) atomicAdd(deg + dst, 1.0f);
    }
}

// ---------------- fused SAGEConv + LayerNorm + ReLU ----------------
// 1024 threads = 16 waves share the 132KB weight LDS (4 waves/SIMD).
// One wave per node; lane l computes output features l and l+64.
// deg==nullptr means agg is already mean-normalized.
__global__ __launch_bounds__(1024) void sage_kernel(
        const float* __restrict__ x,
        const float* __restrict__ agg_in,   // aliases d_out (row n fully read before written)
        const float* __restrict__ deg,
        const float* __restrict__ Wl,
        const float* __restrict__ bl,
        const float* __restrict__ Wr,
        const float* __restrict__ gamma,
        const float* __restrict__ beta,
        float* __restrict__ out,
        int n_nodes) {
    __shared__ float wlt[128 * 129];
    __shared__ float wrt[128 * 129];
    __shared__ float rows[16][256];

    int tid = threadIdx.x;
    for (int i = tid; i < 128 * 128; i += 1024) {
        int d = i >> 7;
        int k = i & 127;
        wlt[k * 129 + d] = Wl[i];
        wrt[k * 129 + d] = Wr[i];
    }
    __syncthreads();

    int wave = tid >> 6;
    int lane = tid & 63;
    int gwave = blockIdx.x * 16 + wave;
    int nwaves = gridDim.x * 16;
    float* row = rows[wave];

    int d0 = lane, d1 = lane + 64;
    float bl0 = bl[d0], bl1 = bl[d1];
    float g0 = gamma[d0], g1 = gamma[d1];
    float be0 = beta[d0], be1 = beta[d1];

    for (int n = gwave; n < n_nodes; n += nwaves) {
        float inv = 1.0f;
        if (deg) inv = 1.0f / fmaxf(deg[n], 1.0f);
        long long base = (long long)n * D;
        row[lane]       = agg_in[base + lane] * inv;
        row[lane + 64]  = agg_in[base + lane + 64] * inv;
        row[lane + 128] = x[base + lane];
        row[lane + 192] = x[base + lane + 64];

        float acc0 = bl0, acc1 = bl1;
        #pragma unroll 4
        for (int k = 0; k < 128; ++k) {
            float a  = row[k];
            float xv = row[128 + k];
            acc0 += a * wlt[k * 129 + d0];
            acc1 += a * wlt[k * 129 + d1];
            acc0 += xv * wrt[k * 129 + d0];
            acc1 += xv * wrt[k * 129 + d1];
        }

        float s  = acc0 + acc1;
        float sq = acc0 * acc0 + acc1 * acc1;
        #pragma unroll
        for (int off = 32; off >= 1; off >>= 1) {
            s  += __shfl_xor(s, off, 64);
            sq += __shfl_xor(sq, off, 64);
        }
        float mu   = s * (1.0f / 128.0f);
        float var  = sq * (1.0f / 128.0f) - mu * mu;
        float rstd = rsqrtf(var + 1e-5f);
        float o0 = (acc0 - mu) * rstd * g0 + be0;
        float o1 = (acc1 - mu) * rstd * g1 + be1;
        out[base + d0] = fmaxf(o0, 0.0f);
        out[base + d1] = fmaxf(o1, 0.0f);
    }
}

extern "C" void kernel_launch(void* const* d_in, const int* in_sizes, int n_in,
                              void* d_out, int out_size, void* d_ws, size_t ws_size,
                              hipStream_t stream) {
    const float* x     = (const float*)d_in[0];
    const int*   ei    = (const int*)d_in[1];
    const float* Wl    = (const float*)d_in[2];
    const float* bl    = (const float*)d_in[3];
    const float* Wr    = (const float*)d_in[4];
    const float* gamma = (const float*)d_in[5];
    const float* beta  = (const float*)d_in[6];

    int n_nodes = in_sizes[0] / D;
    int n_edges = in_sizes[1] / 2;

    float* agg = (float*)d_out;   // reuse d_out as the aggregation buffer

    // ws layout: deg[N] | offs[N+1] | cursor[N] | csr[E]   (ints)
    size_t need = ((size_t)n_nodes * 3 + 1 + (size_t)n_edges) * sizeof(int);

    if (ws_size >= need) {
        int* deg    = (int*)d_ws;
        int* offs   = deg + n_nodes;
        int* cursor = offs + n_nodes + 1;
        int* csr    = cursor + n_nodes;

        zero_int<<<256, 256, 0, stream>>>(deg, n_nodes);
        count_kernel<<<2048, 256, 0, stream>>>(ei, deg, n_edges);
        scan_kernel<<<1, 1024, 0, stream>>>(deg, offs, cursor, n_nodes);
        fill_kernel<<<2048, 256, 0, stream>>>(ei, cursor, csr, n_edges);
        gather_kernel<<<2048, 256, 0, stream>>>(x, offs, csr, agg, n_nodes);
        sage_kernel<<<512, 1024, 0, stream>>>(x, agg, nullptr, Wl, bl, Wr, gamma, beta,
                                              (float*)d_out, n_nodes);
    } else {
        float* degf = (float*)d_ws;  // N floats
        zero_f<<<2048, 256, 0, stream>>>(agg, degf, n_nodes);
        scatter_kernel<<<2048, 256, 0, stream>>>(x, ei, agg, degf, n_edges);
        sage_kernel<<<512, 1024, 0, stream>>>(x, agg, degf, Wl, bl, Wr, gamma, beta,
                                              (float*)d_out, n_nodes);
    }
}

// Round 3
// 645.212 us; speedup vs baseline: 4.9884x; 1.1598x over previous
//
#include <hip/hip_runtime.h>

// GraphSAGE block: CSR-gather mean -> SAGEConv (MFMA bf16) -> LayerNorm -> ReLU
// N=100000, E=1600000, D_IN=D_OUT=128

#define D 128

typedef __attribute__((ext_vector_type(8))) short bf16x8;   // 8 bf16 in 4 VGPRs
typedef __attribute__((ext_vector_type(4))) float f32x4;

__device__ inline unsigned short f2bf(float f) {            // f32 -> bf16 RNE
    unsigned int u = __builtin_bit_cast(unsigned int, f);
    u += 0x7FFFu + ((u >> 16) & 1u);
    return (unsigned short)(u >> 16);
}

// ---------------- zero int array ----------------
__global__ void zero_int(int* __restrict__ p, int n) {
    for (int i = blockIdx.x * blockDim.x + threadIdx.x; i < n;
         i += gridDim.x * blockDim.x) p[i] = 0;
}

// ---------------- count degrees ----------------
__global__ void count_kernel(const int* __restrict__ ei, int* __restrict__ deg, int n_edges) {
    for (int e = blockIdx.x * blockDim.x + threadIdx.x; e < n_edges;
         e += gridDim.x * blockDim.x)
        atomicAdd(&deg[ei[n_edges + e]], 1);
}

// ---------------- blocked exclusive scan, single block ----------------
__global__ __launch_bounds__(1024) void scan_kernel(const int* __restrict__ deg,
                                                    int* __restrict__ offs,
                                                    int* __restrict__ cursor, int n) {
    __shared__ int partial[1024];
    int tid = threadIdx.x;
    int chunk = (n + 1023) >> 10;
    int s0 = tid * chunk;
    int s1 = min(s0 + chunk, n);
    int sum = 0;
    for (int i = s0; i < s1; ++i) sum += deg[i];
    partial[tid] = sum;
    __syncthreads();
    for (int off = 1; off < 1024; off <<= 1) {
        int t = (tid >= off) ? partial[tid - off] : 0;
        __syncthreads();
        partial[tid] += t;
        __syncthreads();
    }
    int run = partial[tid] - sum;   // exclusive prefix of this chunk
    for (int i = s0; i < s1; ++i) {
        offs[i] = run; cursor[i] = run; run += deg[i];
    }
    if (tid == 1023) offs[n] = run;
}

// ---------------- fill CSR neighbor lists ----------------
__global__ void fill_kernel(const int* __restrict__ ei, int* __restrict__ cursor,
                            int* __restrict__ csr, int n_edges) {
    for (int e = blockIdx.x * blockDim.x + threadIdx.x; e < n_edges;
         e += gridDim.x * blockDim.x) {
        int src = ei[e];
        int dst = ei[n_edges + e];
        int pos = atomicAdd(&cursor[dst], 1);
        csr[pos] = src;
    }
}

// ---------------- per-node gather + mean (wave per node) ----------------
template <int BF16OUT>
__global__ void gather_kernel(const float* __restrict__ x,
                              const int* __restrict__ offs,
                              const int* __restrict__ csr,
                              void* __restrict__ agg, int n_nodes) {
    int lane = threadIdx.x & 63;
    int gw = (blockIdx.x * blockDim.x + threadIdx.x) >> 6;
    int nw = (gridDim.x * blockDim.x) >> 6;
    for (int node = gw; node < n_nodes; node += nw) {
        int o0 = offs[node], o1 = offs[node + 1];
        float ax = 0.0f, ay = 0.0f;
        for (int i = o0; i < o1; ++i) {
            int src = csr[i];
            float2 v = reinterpret_cast<const float2*>(x)[src * 64 + lane];
            ax += v.x; ay += v.y;
        }
        float inv = 1.0f / fmaxf((float)(o1 - o0), 1.0f);
        ax *= inv; ay *= inv;
        if (BF16OUT) {
            unsigned int p = (unsigned int)f2bf(ax) | ((unsigned int)f2bf(ay) << 16);
            reinterpret_cast<unsigned int*>(agg)[node * 64 + lane] = p;
        } else {
            float2 r; r.x = ax; r.y = ay;
            reinterpret_cast<float2*>(agg)[node * 64 + lane] = r;
        }
    }
}

// ---------------- fused MFMA SAGEConv + LayerNorm + ReLU ----------------
// 256 threads = 4 waves; each wave computes a 16-node x 128-feature tile.
// C = A_cat[N x 256] @ W_cat^T, W_cat = [Wl | Wr] (128 out x 256 in), + bl, LN, ReLU.
// W_cat staged in LDS in MFMA fragment order (64KB), read as lane-contiguous b128.
template <int AGG_BF16>
__global__ __launch_bounds__(256) void sage_mfma(
        const float* __restrict__ x,
        const void* __restrict__ aggv,      // bf16[N][128] (ws) or f32[N][128] (= d_out)
        const float* __restrict__ Wl,
        const float* __restrict__ bl,
        const float* __restrict__ Wr,
        const float* __restrict__ gamma,
        const float* __restrict__ beta,
        float* __restrict__ out,
        int n_nodes) {
    __shared__ short wfrag[8 * 8 * 64 * 8];   // [n0][kk][lane][8] bf16 = 64KB

    int tid = threadIdx.x;
    // stage W_cat in fragment order: element (n0,kk,lane,j) = W_cat[n0*16+(lane&15)][kk*32+8*(lane>>4)+j]
    for (int e = tid; e < 32768; e += 256) {
        int j = e & 7, lane_ = (e >> 3) & 63, kk = (e >> 9) & 7, n0 = e >> 12;
        int dd = n0 * 16 + (lane_ & 15);
        int k = kk * 32 + 8 * (lane_ >> 4) + j;
        float w = (k < 128) ? Wl[dd * 128 + k] : Wr[dd * 128 + (k - 128)];
        wfrag[e] = (short)f2bf(w);
    }
    __syncthreads();

    int wave = tid >> 6, lane = tid & 63;
    int sl = lane & 15, g = lane >> 4;
    int gw = blockIdx.x * 4 + wave;
    int nw = gridDim.x * 4;
    int ntiles = (n_nodes + 15) >> 4;

    // per-lane epilogue constants (feature d = n0*16 + sl)
    float blv[8], gmv[8], btv[8];
    #pragma unroll
    for (int n0 = 0; n0 < 8; ++n0) {
        blv[n0] = bl[n0 * 16 + sl];
        gmv[n0] = gamma[n0 * 16 + sl];
        btv[n0] = beta[n0 * 16 + sl];
    }

    const bf16x8* wf = reinterpret_cast<const bf16x8*>(wfrag);

    for (int t = gw; t < ntiles; t += nw) {
        int R0 = t << 4;
        int node = R0 + sl;
        if (node >= n_nodes) node = n_nodes - 1;   // clamp (N%16==0 here anyway)

        bf16x8 va[8];
        // A rows, k<128: aggregated neighbors
        if (AGG_BF16) {
            const bf16x8* ar = reinterpret_cast<const bf16x8*>(aggv) + (size_t)node * 16;
            #pragma unroll
            for (int kk = 0; kk < 4; ++kk) va[kk] = ar[kk * 4 + g];
        } else {
            const float* ar = reinterpret_cast<const float*>(aggv) + (size_t)node * 128;
            #pragma unroll
            for (int kk = 0; kk < 4; ++kk) {
                int base = kk * 32 + 8 * g;
                float4 u0 = *reinterpret_cast<const float4*>(ar + base);
                float4 u1 = *reinterpret_cast<const float4*>(ar + base + 4);
                bf16x8 v;
                v[0] = (short)f2bf(u0.x); v[1] = (short)f2bf(u0.y);
                v[2] = (short)f2bf(u0.z); v[3] = (short)f2bf(u0.w);
                v[4] = (short)f2bf(u1.x); v[5] = (short)f2bf(u1.y);
                v[6] = (short)f2bf(u1.z); v[7] = (short)f2bf(u1.w);
                va[kk] = v;
            }
        }
        // A rows, k>=128: root features x
        {
            const float* xr = x + (size_t)node * 128;
            #pragma unroll
            for (int kk = 0; kk < 4; ++kk) {
                int base = kk * 32 + 8 * g;
                float4 u0 = *reinterpret_cast<const float4*>(xr + base);
                float4 u1 = *reinterpret_cast<const float4*>(xr + base + 4);
                bf16x8 v;
                v[0] = (short)f2bf(u0.x); v[1] = (short)f2bf(u0.y);
                v[2] = (short)f2bf(u0.z); v[3] = (short)f2bf(u0.w);
                v[4] = (short)f2bf(u1.x); v[5] = (short)f2bf(u1.y);
                v[6] = (short)f2bf(u1.z); v[7] = (short)f2bf(u1.w);
                va[4 + kk] = v;
            }
        }

        f32x4 acc[8];
        #pragma unroll
        for (int n0 = 0; n0 < 8; ++n0) acc[n0] = (f32x4){0.f, 0.f, 0.f, 0.f};

        #pragma unroll
        for (int n0 = 0; n0 < 8; ++n0)
            #pragma unroll
            for (int kk = 0; kk < 8; ++kk)
                acc[n0] = __builtin_amdgcn_mfma_f32_16x16x32_bf16(
                    va[kk], wf[(n0 * 8 + kk) * 64 + lane], acc[n0], 0, 0, 0);

        // + bias, then LayerNorm per node (node m = R0 + 4*g + r; its features live
        // in the 16 lanes of this group at register r across the 8 tiles)
        float s[4] = {0.f, 0.f, 0.f, 0.f}, sq[4] = {0.f, 0.f, 0.f, 0.f};
        #pragma unroll
        for (int n0 = 0; n0 < 8; ++n0) {
            #pragma unroll
            for (int r = 0; r < 4; ++r) {
                float v = acc[n0][r] + blv[n0];
                acc[n0][r] = v;
                s[r] += v; sq[r] += v * v;
            }
        }
        #pragma unroll
        for (int off = 1; off <= 8; off <<= 1) {
            #pragma unroll
            for (int r = 0; r < 4; ++r) {
                s[r]  += __shfl_xor(s[r], off, 64);
                sq[r] += __shfl_xor(sq[r], off, 64);
            }
        }
        float mu[4], rstd[4];
        #pragma unroll
        for (int r = 0; r < 4; ++r) {
            mu[r] = s[r] * (1.0f / 128.0f);
            float var = sq[r] * (1.0f / 128.0f) - mu[r] * mu[r];
            rstd[r] = rsqrtf(var + 1e-5f);
        }
        #pragma unroll
        for (int n0 = 0; n0 < 8; ++n0) {
            #pragma unroll
            for (int r = 0; r < 4; ++r) {
                int m = R0 + 4 * g + r;
                if (m < n_nodes) {
                    float o = (acc[n0][r] - mu[r]) * rstd[r] * gmv[n0] + btv[n0];
                    out[(size_t)m * 128 + n0 * 16 + sl] = fmaxf(o, 0.0f);
                }
            }
        }
    }
}

// ---------------- deep fallback (atomic scatter + scalar sage) ----------------
__global__ void zero_f(float* __restrict__ a, float* __restrict__ dg, int n_nodes) {
    int total = n_nodes * D + n_nodes;
    for (int i = blockIdx.x * blockDim.x + threadIdx.x; i < total;
         i += gridDim.x * blockDim.x) {
        if (i < n_nodes * D) a[i] = 0.0f;
        else                 dg[i - n_nodes * D] = 0.0f;
    }
}
__global__ void scatter_kernel(const float* __restrict__ x, const int* __restrict__ ei,
                               float* __restrict__ agg, float* __restrict__ deg, int n_edges) {
    long long total = (long long)n_edges * 32;
    for (long long idx = blockIdx.x * (long long)blockDim.x + threadIdx.x; idx < total;
         idx += (long long)gridDim.x * blockDim.x) {
        int e = (int)(idx >> 5);
        int j = (int)(idx & 31);
        int src = ei[e];
        int dst = ei[n_edges + e];
        float4 v = reinterpret_cast<const float4*>(x)[(long long)src * 32 + j];
        float* a = agg + (long long)dst * D + j * 4;
        atomicAdd(a + 0, v.x); atomicAdd(a + 1, v.y);
        atomicAdd(a + 2, v.z); atomicAdd(a + 3, v.w);
        if (j == 0) atomicAdd(deg + dst, 1.0f);
    }
}
__global__ __launch_bounds__(1024) void sage_scalar(
        const float* __restrict__ x, const float* __restrict__ agg_in,
        const float* __restrict__ deg,
        const float* __restrict__ Wl, const float* __restrict__ bl,
        const float* __restrict__ Wr,
        const float* __restrict__ gamma, const float* __restrict__ beta,
        float* __restrict__ out, int n_nodes) {
    __shared__ float wlt[128 * 129];
    __shared__ float wrt[128 * 129];
    __shared__ float rows[16][256];
    int tid = threadIdx.x;
    for (int i = tid; i < 128 * 128; i += 1024) {
        int d = i >> 7, k = i & 127;
        wlt[k * 129 + d] = Wl[i];
        wrt[k * 129 + d] = Wr[i];
    }
    __syncthreads();
    int wave = tid >> 6, lane = tid & 63;
    int gwave = blockIdx.x * 16 + wave;
    int nwaves = gridDim.x * 16;
    float* row = rows[wave];
    int d0 = lane, d1 = lane + 64;
    float bl0 = bl[d0], bl1 = bl[d1];
    float g0 = gamma[d0], g1 = gamma[d1];
    float be0 = beta[d0], be1 = beta[d1];
    for (int n = gwave; n < n_nodes; n += nwaves) {
        float inv = 1.0f / fmaxf(deg[n], 1.0f);
        long long base = (long long)n * D;
        row[lane]       = agg_in[base + lane] * inv;
        row[lane + 64]  = agg_in[base + lane + 64] * inv;
        row[lane + 128] = x[base + lane];
        row[lane + 192] = x[base + lane + 64];
        float acc0 = bl0, acc1 = bl1;
        #pragma unroll 4
        for (int k = 0; k < 128; ++k) {
            float a  = row[k];
            float xv = row[128 + k];
            acc0 += a * wlt[k * 129 + d0];
            acc1 += a * wlt[k * 129 + d1];
            acc0 += xv * wrt[k * 129 + d0];
            acc1 += xv * wrt[k * 129 + d1];
        }
        float s  = acc0 + acc1;
        float sq = acc0 * acc0 + acc1 * acc1;
        #pragma unroll
        for (int off = 32; off >= 1; off >>= 1) {
            s  += __shfl_xor(s, off, 64);
            sq += __shfl_xor(sq, off, 64);
        }
        float mu = s * (1.0f / 128.0f);
        float var = sq * (1.0f / 128.0f) - mu * mu;
        float rstd = rsqrtf(var + 1e-5f);
        float o0 = (acc0 - mu) * rstd * g0 + be0;
        float o1 = (acc1 - mu) * rstd * g1 + be1;
        out[base + d0] = fmaxf(o0, 0.0f);
        out[base + d1] = fmaxf(o1, 0.0f);
    }
}

extern "C" void kernel_launch(void* const* d_in, const int* in_sizes, int n_in,
                              void* d_out, int out_size, void* d_ws, size_t ws_size,
                              hipStream_t stream) {
    const float* x     = (const float*)d_in[0];
    const int*   ei    = (const int*)d_in[1];
    const float* Wl    = (const float*)d_in[2];
    const float* bl    = (const float*)d_in[3];
    const float* Wr    = (const float*)d_in[4];
    const float* gamma = (const float*)d_in[5];
    const float* beta  = (const float*)d_in[6];

    int n_nodes = in_sizes[0] / D;
    int n_edges = in_sizes[1] / 2;

    // ws layout: deg[N] | offs[N+1] | cursor[N] | csr[E] (ints) | [aligned] agg_bf16[N*128]
    size_t int_bytes  = ((size_t)n_nodes * 3 + 1 + (size_t)n_edges) * sizeof(int);
    size_t aggb_off   = (int_bytes + 255) & ~(size_t)255;
    size_t need_a     = aggb_off + (size_t)n_nodes * 128 * 2;
    size_t need_b     = int_bytes;

    if (ws_size >= need_b) {
        int* deg    = (int*)d_ws;
        int* offs   = deg + n_nodes;
        int* cursor = offs + n_nodes + 1;
        int* csr    = cursor + n_nodes;

        zero_int<<<256, 256, 0, stream>>>(deg, n_nodes);
        count_kernel<<<2048, 256, 0, stream>>>(ei, deg, n_edges);
        scan_kernel<<<1, 1024, 0, stream>>>(deg, offs, cursor, n_nodes);
        fill_kernel<<<2048, 256, 0, stream>>>(ei, cursor, csr, n_edges);

        if (ws_size >= need_a) {
            void* aggb = (char*)d_ws + aggb_off;
            gather_kernel<1><<<2048, 256, 0, stream>>>(x, offs, csr, aggb, n_nodes);
            sage_mfma<1><<<512, 256, 0, stream>>>(x, aggb, Wl, bl, Wr, gamma, beta,
                                                  (float*)d_out, n_nodes);
        } else {
            float* aggf = (float*)d_out;   // reuse d_out; rows read before written
            gather_kernel<0><<<2048, 256, 0, stream>>>(x, offs, csr, aggf, n_nodes);
            sage_mfma<0><<<512, 256, 0, stream>>>(x, aggf, Wl, bl, Wr, gamma, beta,
                                                  (float*)d_out, n_nodes);
        }
    } else {
        float* degf = (float*)d_ws;
        zero_f<<<2048, 256, 0, stream>>>((float*)d_out, degf, n_nodes);
        scatter_kernel<<<2048, 256, 0, stream>>>(x, ei, (float*)d_out, degf, n_edges);
        sage_scalar<<<512, 1024, 0, stream>>>(x, (float*)d_out, degf, Wl, bl, Wr,
                                              gamma, beta, (float*)d_out, n_nodes);
    }
}

// Round 4
// 440.605 us; speedup vs baseline: 7.3049x; 1.4644x over previous
//
#include <hip/hip_runtime.h>

// GraphSAGE block: CSR-gather mean -> SAGEConv (MFMA bf16) -> LayerNorm -> ReLU
// N=100000, E=1600000, D_IN=D_OUT=128

#define D 128
#define SCAN_NB 256   // blocks in multi-block scan

typedef __attribute__((ext_vector_type(8))) short bf16x8;   // 8 bf16 in 4 VGPRs
typedef __attribute__((ext_vector_type(4))) float f32x4;

__device__ inline unsigned short f2bf(float f) {            // f32 -> bf16 RNE
    unsigned int u = __builtin_bit_cast(unsigned int, f);
    u += 0x7FFFu + ((u >> 16) & 1u);
    return (unsigned short)(u >> 16);
}

// ---------------- count degrees ----------------
__global__ void count_kernel(const int* __restrict__ ei, int* __restrict__ deg, int n_edges) {
    for (int e = blockIdx.x * blockDim.x + threadIdx.x; e < n_edges;
         e += gridDim.x * blockDim.x)
        atomicAdd(&deg[ei[n_edges + e]], 1);
}

// ---------------- multi-block exclusive scan, 3 phases ----------------
// A: block b sums its chunk of deg -> bsum[b]
__global__ __launch_bounds__(256) void scan_partA(const int* __restrict__ deg,
                                                  int* __restrict__ bsum, int n) {
    __shared__ int red[256];
    int b = blockIdx.x;
    int chunk = (n + SCAN_NB - 1) / SCAN_NB;
    int s0 = b * chunk, s1 = min(s0 + chunk, n);
    int sum = 0;
    for (int i = s0 + threadIdx.x; i < s1; i += 256) sum += deg[i];
    red[threadIdx.x] = sum;
    __syncthreads();
    for (int off = 128; off >= 1; off >>= 1) {
        if (threadIdx.x < off) red[threadIdx.x] += red[threadIdx.x + off];
        __syncthreads();
    }
    if (threadIdx.x == 0) bsum[b] = red[0];
}

// B: exclusive-scan the SCAN_NB block sums; also write offs[n] = total
__global__ __launch_bounds__(SCAN_NB) void scan_partB(const int* __restrict__ bsum,
                                                      int* __restrict__ boff,
                                                      int* __restrict__ offs, int n) {
    __shared__ int tmp[SCAN_NB];
    int tid = threadIdx.x;
    int v = bsum[tid];
    tmp[tid] = v;
    __syncthreads();
    for (int off = 1; off < SCAN_NB; off <<= 1) {
        int t = (tid >= off) ? tmp[tid - off] : 0;
        __syncthreads();
        tmp[tid] += t;
        __syncthreads();
    }
    boff[tid] = tmp[tid] - v;
    if (tid == SCAN_NB - 1) offs[n] = tmp[tid];
}

// C: block b writes exclusive scan of its chunk (+boff[b]) into offs and cursor
__global__ __launch_bounds__(256) void scan_partC(const int* __restrict__ deg,
                                                  const int* __restrict__ boff,
                                                  int* __restrict__ offs,
                                                  int* __restrict__ cursor, int n) {
    __shared__ int tsum[256];
    int b = blockIdx.x;
    int chunk = (n + SCAN_NB - 1) / SCAN_NB;
    int s0 = b * chunk, s1 = min(s0 + chunk, n);
    int tchunk = (chunk + 255) >> 8;
    int t0 = s0 + threadIdx.x * tchunk;
    int t1 = min(t0 + tchunk, s1);
    int sum = 0;
    for (int i = t0; i < t1; ++i) sum += deg[i];
    tsum[threadIdx.x] = sum;
    __syncthreads();
    for (int off = 1; off < 256; off <<= 1) {
        int t = (threadIdx.x >= off) ? tsum[threadIdx.x - off] : 0;
        __syncthreads();
        tsum[threadIdx.x] += t;
        __syncthreads();
    }
    int run = boff[b] + tsum[threadIdx.x] - sum;
    for (int i = t0; i < t1; ++i) {
        offs[i] = run; cursor[i] = run; run += deg[i];
    }
}

// ---------------- fill CSR neighbor lists ----------------
__global__ void fill_kernel(const int* __restrict__ ei, int* __restrict__ cursor,
                            int* __restrict__ csr, int n_edges) {
    for (int e = blockIdx.x * blockDim.x + threadIdx.x; e < n_edges;
         e += gridDim.x * blockDim.x) {
        int src = ei[e];
        int dst = ei[n_edges + e];
        int pos = atomicAdd(&cursor[dst], 1);
        csr[pos] = src;
    }
}

// ---------------- per-node gather + mean (wave per node) ----------------
template <int BF16OUT>
__global__ void gather_kernel(const float* __restrict__ x,
                              const int* __restrict__ offs,
                              const int* __restrict__ csr,
                              void* __restrict__ agg, int n_nodes) {
    int lane = threadIdx.x & 63;
    int gw = (blockIdx.x * blockDim.x + threadIdx.x) >> 6;
    int nw = (gridDim.x * blockDim.x) >> 6;
    for (int node = gw; node < n_nodes; node += nw) {
        int o0 = offs[node], o1 = offs[node + 1];
        float ax = 0.0f, ay = 0.0f;
        for (int i = o0; i < o1; ++i) {
            int src = csr[i];
            float2 v = reinterpret_cast<const float2*>(x)[src * 64 + lane];
            ax += v.x; ay += v.y;
        }
        float inv = 1.0f / fmaxf((float)(o1 - o0), 1.0f);
        ax *= inv; ay *= inv;
        if (BF16OUT) {
            unsigned int p = (unsigned int)f2bf(ax) | ((unsigned int)f2bf(ay) << 16);
            reinterpret_cast<unsigned int*>(agg)[node * 64 + lane] = p;
        } else {
            float2 r; r.x = ax; r.y = ay;
            reinterpret_cast<float2*>(agg)[node * 64 + lane] = r;
        }
    }
}

// ---------------- fused MFMA SAGEConv + LayerNorm + ReLU ----------------
// 256 threads = 4 waves; each wave computes a 16-node x 128-feature tile.
// C = A_cat[N x 256] @ W_cat^T, W_cat = [Wl | Wr] (128 out x 256 in), + bl, LN, ReLU.
template <int AGG_BF16>
__global__ __launch_bounds__(256) void sage_mfma(
        const float* __restrict__ x,
        const void* __restrict__ aggv,      // bf16[N][128] (ws) or f32[N][128] (= d_out)
        const float* __restrict__ Wl,
        const float* __restrict__ bl,
        const float* __restrict__ Wr,
        const float* __restrict__ gamma,
        const float* __restrict__ beta,
        float* __restrict__ out,
        int n_nodes) {
    __shared__ short wfrag[8 * 8 * 64 * 8];   // [n0][kk][lane][8] bf16 = 64KB

    int tid = threadIdx.x;
    for (int e = tid; e < 32768; e += 256) {
        int j = e & 7, lane_ = (e >> 3) & 63, kk = (e >> 9) & 7, n0 = e >> 12;
        int dd = n0 * 16 + (lane_ & 15);
        int k = kk * 32 + 8 * (lane_ >> 4) + j;
        float w = (k < 128) ? Wl[dd * 128 + k] : Wr[dd * 128 + (k - 128)];
        wfrag[e] = (short)f2bf(w);
    }
    __syncthreads();

    int wave = tid >> 6, lane = tid & 63;
    int sl = lane & 15, g = lane >> 4;
    int gw = blockIdx.x * 4 + wave;
    int nw = gridDim.x * 4;
    int ntiles = (n_nodes + 15) >> 4;

    float blv[8], gmv[8], btv[8];
    #pragma unroll
    for (int n0 = 0; n0 < 8; ++n0) {
        blv[n0] = bl[n0 * 16 + sl];
        gmv[n0] = gamma[n0 * 16 + sl];
        btv[n0] = beta[n0 * 16 + sl];
    }

    const bf16x8* wf = reinterpret_cast<const bf16x8*>(wfrag);

    for (int t = gw; t < ntiles; t += nw) {
        int R0 = t << 4;
        int node = R0 + sl;
        if (node >= n_nodes) node = n_nodes - 1;

        bf16x8 va[8];
        if (AGG_BF16) {
            const bf16x8* ar = reinterpret_cast<const bf16x8*>(aggv) + (size_t)node * 16;
            #pragma unroll
            for (int kk = 0; kk < 4; ++kk) va[kk] = ar[kk * 4 + g];
        } else {
            const float* ar = reinterpret_cast<const float*>(aggv) + (size_t)node * 128;
            #pragma unroll
            for (int kk = 0; kk < 4; ++kk) {
                int base = kk * 32 + 8 * g;
                float4 u0 = *reinterpret_cast<const float4*>(ar + base);
                float4 u1 = *reinterpret_cast<const float4*>(ar + base + 4);
                bf16x8 v;
                v[0] = (short)f2bf(u0.x); v[1] = (short)f2bf(u0.y);
                v[2] = (short)f2bf(u0.z); v[3] = (short)f2bf(u0.w);
                v[4] = (short)f2bf(u1.x); v[5] = (short)f2bf(u1.y);
                v[6] = (short)f2bf(u1.z); v[7] = (short)f2bf(u1.w);
                va[kk] = v;
            }
        }
        {
            const float* xr = x + (size_t)node * 128;
            #pragma unroll
            for (int kk = 0; kk < 4; ++kk) {
                int base = kk * 32 + 8 * g;
                float4 u0 = *reinterpret_cast<const float4*>(xr + base);
                float4 u1 = *reinterpret_cast<const float4*>(xr + base + 4);
                bf16x8 v;
                v[0] = (short)f2bf(u0.x); v[1] = (short)f2bf(u0.y);
                v[2] = (short)f2bf(u0.z); v[3] = (short)f2bf(u0.w);
                v[4] = (short)f2bf(u1.x); v[5] = (short)f2bf(u1.y);
                v[6] = (short)f2bf(u1.z); v[7] = (short)f2bf(u1.w);
                va[4 + kk] = v;
            }
        }

        f32x4 acc[8];
        #pragma unroll
        for (int n0 = 0; n0 < 8; ++n0) acc[n0] = (f32x4){0.f, 0.f, 0.f, 0.f};

        #pragma unroll
        for (int n0 = 0; n0 < 8; ++n0)
            #pragma unroll
            for (int kk = 0; kk < 8; ++kk)
                acc[n0] = __builtin_amdgcn_mfma_f32_16x16x32_bf16(
                    va[kk], wf[(n0 * 8 + kk) * 64 + lane], acc[n0], 0, 0, 0);

        float s[4] = {0.f, 0.f, 0.f, 0.f}, sq[4] = {0.f, 0.f, 0.f, 0.f};
        #pragma unroll
        for (int n0 = 0; n0 < 8; ++n0) {
            #pragma unroll
            for (int r = 0; r < 4; ++r) {
                float v = acc[n0][r] + blv[n0];
                acc[n0][r] = v;
                s[r] += v; sq[r] += v * v;
            }
        }
        #pragma unroll
        for (int off = 1; off <= 8; off <<= 1) {
            #pragma unroll
            for (int r = 0; r < 4; ++r) {
                s[r]  += __shfl_xor(s[r], off, 64);
                sq[r] += __shfl_xor(sq[r], off, 64);
            }
        }
        float mu[4], rstd[4];
        #pragma unroll
        for (int r = 0; r < 4; ++r) {
            mu[r] = s[r] * (1.0f / 128.0f);
            float var = sq[r] * (1.0f / 128.0f) - mu[r] * mu[r];
            rstd[r] = rsqrtf(var + 1e-5f);
        }
        #pragma unroll
        for (int n0 = 0; n0 < 8; ++n0) {
            #pragma unroll
            for (int r = 0; r < 4; ++r) {
                int m = R0 + 4 * g + r;
                if (m < n_nodes) {
                    float o = (acc[n0][r] - mu[r]) * rstd[r] * gmv[n0] + btv[n0];
                    out[(size_t)m * 128 + n0 * 16 + sl] = fmaxf(o, 0.0f);
                }
            }
        }
    }
}

// ---------------- deep fallback (atomic scatter + scalar sage) ----------------
__global__ void zero_f(float* __restrict__ a, float* __restrict__ dg, int n_nodes) {
    int total = n_nodes * D + n_nodes;
    for (int i = blockIdx.x * blockDim.x + threadIdx.x; i < total;
         i += gridDim.x * blockDim.x) {
        if (i < n_nodes * D) a[i] = 0.0f;
        else                 dg[i - n_nodes * D] = 0.0f;
    }
}
__global__ void scatter_kernel(const float* __restrict__ x, const int* __restrict__ ei,
                               float* __restrict__ agg, float* __restrict__ deg, int n_edges) {
    long long total = (long long)n_edges * 32;
    for (long long idx = blockIdx.x * (long long)blockDim.x + threadIdx.x; idx < total;
         idx += (long long)gridDim.x * blockDim.x) {
        int e = (int)(idx >> 5);
        int j = (int)(idx & 31);
        int src = ei[e];
        int dst = ei[n_edges + e];
        float4 v = reinterpret_cast<const float4*>(x)[(long long)src * 32 + j];
        float* a = agg + (long long)dst * D + j * 4;
        atomicAdd(a + 0, v.x); atomicAdd(a + 1, v.y);
        atomicAdd(a + 2, v.z); atomicAdd(a + 3, v.w);
        if (j == 0) atomicAdd(deg + dst, 1.0f);
    }
}
__global__ __launch_bounds__(1024) void sage_scalar(
        const float* __restrict__ x, const float* __restrict__ agg_in,
        const float* __restrict__ deg,
        const float* __restrict__ Wl, const float* __restrict__ bl,
        const float* __restrict__ Wr,
        const float* __restrict__ gamma, const float* __restrict__ beta,
        float* __restrict__ out, int n_nodes) {
    __shared__ float wlt[128 * 129];
    __shared__ float wrt[128 * 129];
    __shared__ float rows[16][256];
    int tid = threadIdx.x;
    for (int i = tid; i < 128 * 128; i += 1024) {
        int d = i >> 7, k = i & 127;
        wlt[k * 129 + d] = Wl[i];
        wrt[k * 129 + d] = Wr[i];
    }
    __syncthreads();
    int wave = tid >> 6, lane = tid & 63;
    int gwave = blockIdx.x * 16 + wave;
    int nwaves = gridDim.x * 16;
    float* row = rows[wave];
    int d0 = lane, d1 = lane + 64;
    float bl0 = bl[d0], bl1 = bl[d1];
    float g0 = gamma[d0], g1 = gamma[d1];
    float be0 = beta[d0], be1 = beta[d1];
    for (int n = gwave; n < n_nodes; n += nwaves) {
        float inv = 1.0f / fmaxf(deg[n], 1.0f);
        long long base = (long long)n * D;
        row[lane]       = agg_in[base + lane] * inv;
        row[lane + 64]  = agg_in[base + lane + 64] * inv;
        row[lane + 128] = x[base + lane];
        row[lane + 192] = x[base + lane + 64];
        float acc0 = bl0, acc1 = bl1;
        #pragma unroll 4
        for (int k = 0; k < 128; ++k) {
            float a  = row[k];
            float xv = row[128 + k];
            acc0 += a * wlt[k * 129 + d0];
            acc1 += a * wlt[k * 129 + d1];
            acc0 += xv * wrt[k * 129 + d0];
            acc1 += xv * wrt[k * 129 + d1];
        }
        float s  = acc0 + acc1;
        float sq = acc0 * acc0 + acc1 * acc1;
        #pragma unroll
        for (int off = 32; off >= 1; off >>= 1) {
            s  += __shfl_xor(s, off, 64);
            sq += __shfl_xor(sq, off, 64);
        }
        float mu = s * (1.0f / 128.0f);
        float var = sq * (1.0f / 128.0f) - mu * mu;
        float rstd = rsqrtf(var + 1e-5f);
        float o0 = (acc0 - mu) * rstd * g0 + be0;
        float o1 = (acc1 - mu) * rstd * g1 + be1;
        out[base + d0] = fmaxf(o0, 0.0f);
        out[base + d1] = fmaxf(o1, 0.0f);
    }
}

extern "C" void kernel_launch(void* const* d_in, const int* in_sizes, int n_in,
                              void* d_out, int out_size, void* d_ws, size_t ws_size,
                              hipStream_t stream) {
    const float* x     = (const float*)d_in[0];
    const int*   ei    = (const int*)d_in[1];
    const float* Wl    = (const float*)d_in[2];
    const float* bl    = (const float*)d_in[3];
    const float* Wr    = (const float*)d_in[4];
    const float* gamma = (const float*)d_in[5];
    const float* beta  = (const float*)d_in[6];

    int n_nodes = in_sizes[0] / D;
    int n_edges = in_sizes[1] / 2;

    // ws layout: deg[N] | offs[N+1] | cursor[N] | bsum[256] | boff[256] | csr[E]
    //            | [256-aligned] agg_bf16[N*128]
    size_t int_elems = (size_t)n_nodes * 3 + 1 + 2 * SCAN_NB + (size_t)n_edges;
    size_t int_bytes = int_elems * sizeof(int);
    size_t aggb_off  = (int_bytes + 255) & ~(size_t)255;
    size_t need_a    = aggb_off + (size_t)n_nodes * 128 * 2;
    size_t need_b    = int_bytes;

    if (ws_size >= need_b) {
        int* deg    = (int*)d_ws;
        int* offs   = deg + n_nodes;
        int* cursor = offs + n_nodes + 1;
        int* bsum   = cursor + n_nodes;
        int* boff   = bsum + SCAN_NB;
        int* csr    = boff + SCAN_NB;

        hipMemsetAsync(deg, 0, (size_t)n_nodes * sizeof(int), stream);
        count_kernel<<<2048, 256, 0, stream>>>(ei, deg, n_edges);
        scan_partA<<<SCAN_NB, 256, 0, stream>>>(deg, bsum, n_nodes);
        scan_partB<<<1, SCAN_NB, 0, stream>>>(bsum, boff, offs, n_nodes);
        scan_partC<<<SCAN_NB, 256, 0, stream>>>(deg, boff, offs, cursor, n_nodes);
        fill_kernel<<<2048, 256, 0, stream>>>(ei, cursor, csr, n_edges);

        if (ws_size >= need_a) {
            void* aggb = (char*)d_ws + aggb_off;
            gather_kernel<1><<<2048, 256, 0, stream>>>(x, offs, csr, aggb, n_nodes);
            sage_mfma<1><<<512, 256, 0, stream>>>(x, aggb, Wl, bl, Wr, gamma, beta,
                                                  (float*)d_out, n_nodes);
        } else {
            float* aggf = (float*)d_out;
            gather_kernel<0><<<2048, 256, 0, stream>>>(x, offs, csr, aggf, n_nodes);
            sage_mfma<0><<<512, 256, 0, stream>>>(x, aggf, Wl, bl, Wr, gamma, beta,
                                                  (float*)d_out, n_nodes);
        }
    } else {
        float* degf = (float*)d_ws;
        zero_f<<<2048, 256, 0, stream>>>((float*)d_out, degf, n_nodes);
        scatter_kernel<<<2048, 256, 0, stream>>>(x, ei, (float*)d_out, degf, n_edges);
        sage_scalar<<<512, 1024, 0, stream>>>(x, (float*)d_out, degf, Wl, bl, Wr,
                                              gamma, beta, (float*)d_out, n_nodes);
    }
}

// Round 5
// 371.552 us; speedup vs baseline: 8.6625x; 1.1859x over previous
//
#include <hip/hip_runtime.h>

// GraphSAGE block: bf16-convert -> CSR-gather mean (bf16) -> SAGEConv (MFMA bf16) -> LN -> ReLU
// N=100000, E=1600000, D_IN=D_OUT=128

#define D 128
#define SCAN_NB 256   // blocks in multi-block scan

typedef __attribute__((ext_vector_type(8))) short bf16x8;   // 8 bf16 in 4 VGPRs
typedef __attribute__((ext_vector_type(4))) float f32x4;

__device__ inline unsigned short f2bf(float f) {            // f32 -> bf16 RNE
    unsigned int u = __builtin_bit_cast(unsigned int, f);
    u += 0x7FFFu + ((u >> 16) & 1u);
    return (unsigned short)(u >> 16);
}
__device__ inline float bf_lo(unsigned int u) {             // low bf16 -> f32
    return __builtin_bit_cast(float, u << 16);
}
__device__ inline float bf_hi(unsigned int u) {             // high bf16 -> f32
    return __builtin_bit_cast(float, u & 0xFFFF0000u);
}

// ---------------- convert x (f32) -> xb (bf16), float4 -> uint2 ----------------
__global__ void convert_kernel(const float* __restrict__ x,
                               unsigned int* __restrict__ xb2, long long n4) {
    // n4 = N*128/4 ; xb2 is uint2-viewed as 2 uints per float4
    for (long long i = blockIdx.x * (long long)blockDim.x + threadIdx.x; i < n4;
         i += (long long)gridDim.x * blockDim.x) {
        float4 v = reinterpret_cast<const float4*>(x)[i];
        unsigned int lo = (unsigned int)f2bf(v.x) | ((unsigned int)f2bf(v.y) << 16);
        unsigned int hi = (unsigned int)f2bf(v.z) | ((unsigned int)f2bf(v.w) << 16);
        xb2[2 * i]     = lo;
        xb2[2 * i + 1] = hi;
    }
}

// ---------------- count degrees ----------------
__global__ void count_kernel(const int* __restrict__ ei, int* __restrict__ deg, int n_edges) {
    for (int e = blockIdx.x * blockDim.x + threadIdx.x; e < n_edges;
         e += gridDim.x * blockDim.x)
        atomicAdd(&deg[ei[n_edges + e]], 1);
}

// ---------------- multi-block exclusive scan, 3 phases ----------------
__global__ __launch_bounds__(256) void scan_partA(const int* __restrict__ deg,
                                                  int* __restrict__ bsum, int n) {
    __shared__ int red[256];
    int b = blockIdx.x;
    int chunk = (n + SCAN_NB - 1) / SCAN_NB;
    int s0 = b * chunk, s1 = min(s0 + chunk, n);
    int sum = 0;
    for (int i = s0 + threadIdx.x; i < s1; i += 256) sum += deg[i];
    red[threadIdx.x] = sum;
    __syncthreads();
    for (int off = 128; off >= 1; off >>= 1) {
        if (threadIdx.x < off) red[threadIdx.x] += red[threadIdx.x + off];
        __syncthreads();
    }
    if (threadIdx.x == 0) bsum[b] = red[0];
}

__global__ __launch_bounds__(SCAN_NB) void scan_partB(const int* __restrict__ bsum,
                                                      int* __restrict__ boff,
                                                      int* __restrict__ offs, int n) {
    __shared__ int tmp[SCAN_NB];
    int tid = threadIdx.x;
    int v = bsum[tid];
    tmp[tid] = v;
    __syncthreads();
    for (int off = 1; off < SCAN_NB; off <<= 1) {
        int t = (tid >= off) ? tmp[tid - off] : 0;
        __syncthreads();
        tmp[tid] += t;
        __syncthreads();
    }
    boff[tid] = tmp[tid] - v;
    if (tid == SCAN_NB - 1) offs[n] = tmp[tid];
}

__global__ __launch_bounds__(256) void scan_partC(const int* __restrict__ deg,
                                                  const int* __restrict__ boff,
                                                  int* __restrict__ offs,
                                                  int* __restrict__ cursor, int n) {
    __shared__ int tsum[256];
    int b = blockIdx.x;
    int chunk = (n + SCAN_NB - 1) / SCAN_NB;
    int s0 = b * chunk, s1 = min(s0 + chunk, n);
    int tchunk = (chunk + 255) >> 8;
    int t0 = s0 + threadIdx.x * tchunk;
    int t1 = min(t0 + tchunk, s1);
    int sum = 0;
    for (int i = t0; i < t1; ++i) sum += deg[i];
    tsum[threadIdx.x] = sum;
    __syncthreads();
    for (int off = 1; off < 256; off <<= 1) {
        int t = (threadIdx.x >= off) ? tsum[threadIdx.x - off] : 0;
        __syncthreads();
        tsum[threadIdx.x] += t;
        __syncthreads();
    }
    int run = boff[b] + tsum[threadIdx.x] - sum;
    for (int i = t0; i < t1; ++i) {
        offs[i] = run; cursor[i] = run; run += deg[i];
    }
}

// ---------------- fill CSR neighbor lists ----------------
__global__ void fill_kernel(const int* __restrict__ ei, int* __restrict__ cursor,
                            int* __restrict__ csr, int n_edges) {
    for (int e = blockIdx.x * blockDim.x + threadIdx.x; e < n_edges;
         e += gridDim.x * blockDim.x) {
        int src = ei[e];
        int dst = ei[n_edges + e];
        int pos = atomicAdd(&cursor[dst], 1);
        csr[pos] = src;
    }
}

// ---------------- per-node gather + mean (wave per node) ----------------
// XBSRC=1: read bf16 rows (uint/lane); else f32 rows (float2/lane).
// BF16OUT=1: write packed bf16 agg; else f32 agg.
template <int XBSRC, int BF16OUT>
__global__ void gather_kernel(const void* __restrict__ xsrc,
                              const int* __restrict__ offs,
                              const int* __restrict__ csr,
                              void* __restrict__ agg, int n_nodes) {
    int lane = threadIdx.x & 63;
    int gw = (blockIdx.x * blockDim.x + threadIdx.x) >> 6;
    int nw = (gridDim.x * blockDim.x) >> 6;
    for (int node = gw; node < n_nodes; node += nw) {
        int o0 = offs[node], o1 = offs[node + 1];
        float ax = 0.0f, ay = 0.0f;
        if (XBSRC) {
            const unsigned int* xu = (const unsigned int*)xsrc;
            int i = o0;
            for (; i + 1 < o1; i += 2) {            // 2-way unroll for MLP
                int s0 = csr[i], s1 = csr[i + 1];
                unsigned int u0 = xu[(size_t)s0 * 64 + lane];
                unsigned int u1 = xu[(size_t)s1 * 64 + lane];
                ax += bf_lo(u0); ay += bf_hi(u0);
                ax += bf_lo(u1); ay += bf_hi(u1);
            }
            if (i < o1) {
                unsigned int u0 = xu[(size_t)csr[i] * 64 + lane];
                ax += bf_lo(u0); ay += bf_hi(u0);
            }
        } else {
            const float* xf = (const float*)xsrc;
            for (int i = o0; i < o1; ++i) {
                int src = csr[i];
                float2 v = reinterpret_cast<const float2*>(xf)[(size_t)src * 64 + lane];
                ax += v.x; ay += v.y;
            }
        }
        float inv = 1.0f / fmaxf((float)(o1 - o0), 1.0f);
        ax *= inv; ay *= inv;
        if (BF16OUT) {
            unsigned int p = (unsigned int)f2bf(ax) | ((unsigned int)f2bf(ay) << 16);
            reinterpret_cast<unsigned int*>(agg)[(size_t)node * 64 + lane] = p;
        } else {
            float2 r; r.x = ax; r.y = ay;
            reinterpret_cast<float2*>(agg)[(size_t)node * 64 + lane] = r;
        }
    }
}

// ---------------- fused MFMA SAGEConv + LayerNorm + ReLU ----------------
// 256 threads = 4 waves; each wave computes a 16-node x 128-feature tile.
// C = A_cat[N x 256] @ W_cat^T, W_cat = [Wl | Wr] (128 out x 256 in), + bl, LN, ReLU.
// AGG_BF16: agg buffer dtype. XB16: x source dtype (bf16 'xb' or f32 'x').
template <int AGG_BF16, int XB16>
__global__ __launch_bounds__(256) void sage_mfma(
        const void* __restrict__ xsrc,
        const void* __restrict__ aggv,
        const float* __restrict__ Wl,
        const float* __restrict__ bl,
        const float* __restrict__ Wr,
        const float* __restrict__ gamma,
        const float* __restrict__ beta,
        float* __restrict__ out,
        int n_nodes) {
    __shared__ short wfrag[8 * 8 * 64 * 8];   // [n0][kk][lane][8] bf16 = 64KB

    int tid = threadIdx.x;
    for (int e = tid; e < 32768; e += 256) {
        int j = e & 7, lane_ = (e >> 3) & 63, kk = (e >> 9) & 7, n0 = e >> 12;
        int dd = n0 * 16 + (lane_ & 15);
        int k = kk * 32 + 8 * (lane_ >> 4) + j;
        float w = (k < 128) ? Wl[dd * 128 + k] : Wr[dd * 128 + (k - 128)];
        wfrag[e] = (short)f2bf(w);
    }
    __syncthreads();

    int wave = tid >> 6, lane = tid & 63;
    int sl = lane & 15, g = lane >> 4;
    int gw = blockIdx.x * 4 + wave;
    int nw = gridDim.x * 4;
    int ntiles = (n_nodes + 15) >> 4;

    float blv[8], gmv[8], btv[8];
    #pragma unroll
    for (int n0 = 0; n0 < 8; ++n0) {
        blv[n0] = bl[n0 * 16 + sl];
        gmv[n0] = gamma[n0 * 16 + sl];
        btv[n0] = beta[n0 * 16 + sl];
    }

    const bf16x8* wf = reinterpret_cast<const bf16x8*>(wfrag);

    for (int t = gw; t < ntiles; t += nw) {
        int R0 = t << 4;
        int node = R0 + sl;
        if (node >= n_nodes) node = n_nodes - 1;

        bf16x8 va[8];
        if (AGG_BF16) {
            const bf16x8* ar = reinterpret_cast<const bf16x8*>(aggv) + (size_t)node * 16;
            #pragma unroll
            for (int kk = 0; kk < 4; ++kk) va[kk] = ar[kk * 4 + g];
        } else {
            const float* ar = reinterpret_cast<const float*>(aggv) + (size_t)node * 128;
            #pragma unroll
            for (int kk = 0; kk < 4; ++kk) {
                int base = kk * 32 + 8 * g;
                float4 u0 = *reinterpret_cast<const float4*>(ar + base);
                float4 u1 = *reinterpret_cast<const float4*>(ar + base + 4);
                bf16x8 v;
                v[0] = (short)f2bf(u0.x); v[1] = (short)f2bf(u0.y);
                v[2] = (short)f2bf(u0.z); v[3] = (short)f2bf(u0.w);
                v[4] = (short)f2bf(u1.x); v[5] = (short)f2bf(u1.y);
                v[6] = (short)f2bf(u1.z); v[7] = (short)f2bf(u1.w);
                va[kk] = v;
            }
        }
        if (XB16) {
            const bf16x8* xr = reinterpret_cast<const bf16x8*>(xsrc) + (size_t)node * 16;
            #pragma unroll
            for (int kk = 0; kk < 4; ++kk) va[4 + kk] = xr[kk * 4 + g];
        } else {
            const float* xr = reinterpret_cast<const float*>(xsrc) + (size_t)node * 128;
            #pragma unroll
            for (int kk = 0; kk < 4; ++kk) {
                int base = kk * 32 + 8 * g;
                float4 u0 = *reinterpret_cast<const float4*>(xr + base);
                float4 u1 = *reinterpret_cast<const float4*>(xr + base + 4);
                bf16x8 v;
                v[0] = (short)f2bf(u0.x); v[1] = (short)f2bf(u0.y);
                v[2] = (short)f2bf(u0.z); v[3] = (short)f2bf(u0.w);
                v[4] = (short)f2bf(u1.x); v[5] = (short)f2bf(u1.y);
                v[6] = (short)f2bf(u1.z); v[7] = (short)f2bf(u1.w);
                va[4 + kk] = v;
            }
        }

        f32x4 acc[8];
        #pragma unroll
        for (int n0 = 0; n0 < 8; ++n0) acc[n0] = (f32x4){0.f, 0.f, 0.f, 0.f};

        #pragma unroll
        for (int n0 = 0; n0 < 8; ++n0)
            #pragma unroll
            for (int kk = 0; kk < 8; ++kk)
                acc[n0] = __builtin_amdgcn_mfma_f32_16x16x32_bf16(
                    va[kk], wf[(n0 * 8 + kk) * 64 + lane], acc[n0], 0, 0, 0);

        float s[4] = {0.f, 0.f, 0.f, 0.f}, sq[4] = {0.f, 0.f, 0.f, 0.f};
        #pragma unroll
        for (int n0 = 0; n0 < 8; ++n0) {
            #pragma unroll
            for (int r = 0; r < 4; ++r) {
                float v = acc[n0][r] + blv[n0];
                acc[n0][r] = v;
                s[r] += v; sq[r] += v * v;
            }
        }
        #pragma unroll
        for (int off = 1; off <= 8; off <<= 1) {
            #pragma unroll
            for (int r = 0; r < 4; ++r) {
                s[r]  += __shfl_xor(s[r], off, 64);
                sq[r] += __shfl_xor(sq[r], off, 64);
            }
        }
        float mu[4], rstd[4];
        #pragma unroll
        for (int r = 0; r < 4; ++r) {
            mu[r] = s[r] * (1.0f / 128.0f);
            float var = sq[r] * (1.0f / 128.0f) - mu[r] * mu[r];
            rstd[r] = rsqrtf(var + 1e-5f);
        }
        #pragma unroll
        for (int n0 = 0; n0 < 8; ++n0) {
            #pragma unroll
            for (int r = 0; r < 4; ++r) {
                int m = R0 + 4 * g + r;
                if (m < n_nodes) {
                    float o = (acc[n0][r] - mu[r]) * rstd[r] * gmv[n0] + btv[n0];
                    out[(size_t)m * 128 + n0 * 16 + sl] = fmaxf(o, 0.0f);
                }
            }
        }
    }
}

// ---------------- deep fallback (atomic scatter + scalar sage) ----------------
__global__ void zero_f(float* __restrict__ a, float* __restrict__ dg, int n_nodes) {
    int total = n_nodes * D + n_nodes;
    for (int i = blockIdx.x * blockDim.x + threadIdx.x; i < total;
         i += gridDim.x * blockDim.x) {
        if (i < n_nodes * D) a[i] = 0.0f;
        else                 dg[i - n_nodes * D] = 0.0f;
    }
}
__global__ void scatter_kernel(const float* __restrict__ x, const int* __restrict__ ei,
                               float* __restrict__ agg, float* __restrict__ deg, int n_edges) {
    long long total = (long long)n_edges * 32;
    for (long long idx = blockIdx.x * (long long)blockDim.x + threadIdx.x; idx < total;
         idx += (long long)gridDim.x * blockDim.x) {
        int e = (int)(idx >> 5);
        int j = (int)(idx & 31);
        int src = ei[e];
        int dst = ei[n_edges + e];
        float4 v = reinterpret_cast<const float4*>(x)[(long long)src * 32 + j];
        float* a = agg + (long long)dst * D + j * 4;
        atomicAdd(a + 0, v.x); atomicAdd(a + 1, v.y);
        atomicAdd(a + 2, v.z); atomicAdd(a + 3, v.w);
        if (j == 0) atomicAdd(deg + dst, 1.0f);
    }
}
__global__ __launch_bounds__(1024) void sage_scalar(
        const float* __restrict__ x, const float* __restrict__ agg_in,
        const float* __restrict__ deg,
        const float* __restrict__ Wl, const float* __restrict__ bl,
        const float* __restrict__ Wr,
        const float* __restrict__ gamma, const float* __restrict__ beta,
        float* __restrict__ out, int n_nodes) {
    __shared__ float wlt[128 * 129];
    __shared__ float wrt[128 * 129];
    __shared__ float rows[16][256];
    int tid = threadIdx.x;
    for (int i = tid; i < 128 * 128; i += 1024) {
        int d = i >> 7, k = i & 127;
        wlt[k * 129 + d] = Wl[i];
        wrt[k * 129 + d] = Wr[i];
    }
    __syncthreads();
    int wave = tid >> 6, lane = tid & 63;
    int gwave = blockIdx.x * 16 + wave;
    int nwaves = gridDim.x * 16;
    float* row = rows[wave];
    int d0 = lane, d1 = lane + 64;
    float bl0 = bl[d0], bl1 = bl[d1];
    float g0 = gamma[d0], g1 = gamma[d1];
    float be0 = beta[d0], be1 = beta[d1];
    for (int n = gwave; n < n_nodes; n += nwaves) {
        float inv = 1.0f / fmaxf(deg[n], 1.0f);
        long long base = (long long)n * D;
        row[lane]       = agg_in[base + lane] * inv;
        row[lane + 64]  = agg_in[base + lane + 64] * inv;
        row[lane + 128] = x[base + lane];
        row[lane + 192] = x[base + lane + 64];
        float acc0 = bl0, acc1 = bl1;
        #pragma unroll 4
        for (int k = 0; k < 128; ++k) {
            float a  = row[k];
            float xv = row[128 + k];
            acc0 += a * wlt[k * 129 + d0];
            acc1 += a * wlt[k * 129 + d1];
            acc0 += xv * wrt[k * 129 + d0];
            acc1 += xv * wrt[k * 129 + d1];
        }
        float s  = acc0 + acc1;
        float sq = acc0 * acc0 + acc1 * acc1;
        #pragma unroll
        for (int off = 32; off >= 1; off >>= 1) {
            s  += __shfl_xor(s, off, 64);
            sq += __shfl_xor(sq, off, 64);
        }
        float mu = s * (1.0f / 128.0f);
        float var = sq * (1.0f / 128.0f) - mu * mu;
        float rstd = rsqrtf(var + 1e-5f);
        float o0 = (acc0 - mu) * rstd * g0 + be0;
        float o1 = (acc1 - mu) * rstd * g1 + be1;
        out[base + d0] = fmaxf(o0, 0.0f);
        out[base + d1] = fmaxf(o1, 0.0f);
    }
}

extern "C" void kernel_launch(void* const* d_in, const int* in_sizes, int n_in,
                              void* d_out, int out_size, void* d_ws, size_t ws_size,
                              hipStream_t stream) {
    const float* x     = (const float*)d_in[0];
    const int*   ei    = (const int*)d_in[1];
    const float* Wl    = (const float*)d_in[2];
    const float* bl    = (const float*)d_in[3];
    const float* Wr    = (const float*)d_in[4];
    const float* gamma = (const float*)d_in[5];
    const float* beta  = (const float*)d_in[6];

    int n_nodes = in_sizes[0] / D;
    int n_edges = in_sizes[1] / 2;

    // ws layout: deg[N] | offs[N+1] | cursor[N] | bsum | boff | csr[E] (ints)
    //            | [256-aligned] agg_bf16[N*128] | xb_bf16[N*128]
    size_t int_elems = (size_t)n_nodes * 3 + 1 + 2 * SCAN_NB + (size_t)n_edges;
    size_t int_bytes = int_elems * sizeof(int);
    size_t aggb_off  = (int_bytes + 255) & ~(size_t)255;
    size_t xb_off    = aggb_off + (size_t)n_nodes * 128 * 2;
    size_t need_full = xb_off + (size_t)n_nodes * 128 * 2;
    size_t need_a    = xb_off;            // agg bf16 only
    size_t need_b    = int_bytes;         // CSR only

    if (ws_size >= need_b) {
        int* deg    = (int*)d_ws;
        int* offs   = deg + n_nodes;
        int* cursor = offs + n_nodes + 1;
        int* bsum   = cursor + n_nodes;
        int* boff   = bsum + SCAN_NB;
        int* csr    = boff + SCAN_NB;

        hipMemsetAsync(deg, 0, (size_t)n_nodes * sizeof(int), stream);
        count_kernel<<<2048, 256, 0, stream>>>(ei, deg, n_edges);
        scan_partA<<<SCAN_NB, 256, 0, stream>>>(deg, bsum, n_nodes);
        scan_partB<<<1, SCAN_NB, 0, stream>>>(bsum, boff, offs, n_nodes);
        scan_partC<<<SCAN_NB, 256, 0, stream>>>(deg, boff, offs, cursor, n_nodes);
        fill_kernel<<<2048, 256, 0, stream>>>(ei, cursor, csr, n_edges);

        if (ws_size >= need_full) {
            void* aggb = (char*)d_ws + aggb_off;
            unsigned int* xb = (unsigned int*)((char*)d_ws + xb_off);
            long long n4 = (long long)n_nodes * 32;   // float4 count
            convert_kernel<<<2048, 256, 0, stream>>>(x, xb, n4);
            gather_kernel<1, 1><<<2048, 256, 0, stream>>>(xb, offs, csr, aggb, n_nodes);
            sage_mfma<1, 1><<<512, 256, 0, stream>>>(xb, aggb, Wl, bl, Wr, gamma, beta,
                                                     (float*)d_out, n_nodes);
        } else if (ws_size >= need_a) {
            void* aggb = (char*)d_ws + aggb_off;
            gather_kernel<0, 1><<<2048, 256, 0, stream>>>(x, offs, csr, aggb, n_nodes);
            sage_mfma<1, 0><<<512, 256, 0, stream>>>(x, aggb, Wl, bl, Wr, gamma, beta,
                                                     (float*)d_out, n_nodes);
        } else {
            float* aggf = (float*)d_out;
            gather_kernel<0, 0><<<2048, 256, 0, stream>>>(x, offs, csr, aggf, n_nodes);
            sage_mfma<0, 0><<<512, 256, 0, stream>>>(x, aggf, Wl, bl, Wr, gamma, beta,
                                                     (float*)d_out, n_nodes);
        }
    } else {
        float* degf = (float*)d_ws;
        zero_f<<<2048, 256, 0, stream>>>((float*)d_out, degf, n_nodes);
        scatter_kernel<<<2048, 256, 0, stream>>>(x, ei, (float*)d_out, degf, n_edges);
        sage_scalar<<<512, 1024, 0, stream>>>(x, (float*)d_out, degf, Wl, bl, Wr,
                                              gamma, beta, (float*)d_out, n_nodes);
    }
}

// Round 6
// 277.388 us; speedup vs baseline: 11.6032x; 1.3395x over previous
//
#include <hip/hip_runtime.h>

// GraphSAGE block: bf16-convert -> CSR build (binned fill) -> gather mean -> MFMA SAGE+LN+ReLU
// N=100000, E=1600000, D_IN=D_OUT=128

#define D 128
#define SCAN_NB 256   // blocks in multi-block scan
#define NPB 256       // nodes per dst-bucket (dstLocal fits 8 bits)
#define MAXNB 1024    // max buckets supported by bin_kernel LDS

typedef __attribute__((ext_vector_type(8))) short bf16x8;   // 8 bf16 in 4 VGPRs
typedef __attribute__((ext_vector_type(4))) float f32x4;

__device__ inline unsigned short f2bf(float f) {            // f32 -> bf16 RNE
    unsigned int u = __builtin_bit_cast(unsigned int, f);
    u += 0x7FFFu + ((u >> 16) & 1u);
    return (unsigned short)(u >> 16);
}
__device__ inline float bf_lo(unsigned int u) {
    return __builtin_bit_cast(float, u << 16);
}
__device__ inline float bf_hi(unsigned int u) {
    return __builtin_bit_cast(float, u & 0xFFFF0000u);
}

// ---------------- convert x (f32) -> xb (bf16) ----------------
__global__ void convert_kernel(const float* __restrict__ x,
                               unsigned int* __restrict__ xb2, long long n4) {
    for (long long i = blockIdx.x * (long long)blockDim.x + threadIdx.x; i < n4;
         i += (long long)gridDim.x * blockDim.x) {
        float4 v = reinterpret_cast<const float4*>(x)[i];
        unsigned int lo = (unsigned int)f2bf(v.x) | ((unsigned int)f2bf(v.y) << 16);
        unsigned int hi = (unsigned int)f2bf(v.z) | ((unsigned int)f2bf(v.w) << 16);
        xb2[2 * i]     = lo;
        xb2[2 * i + 1] = hi;
    }
}

// ---------------- count degrees ----------------
__global__ void count_kernel(const int* __restrict__ ei, int* __restrict__ deg, int n_edges) {
    for (int e = blockIdx.x * blockDim.x + threadIdx.x; e < n_edges;
         e += gridDim.x * blockDim.x)
        atomicAdd(&deg[ei[n_edges + e]], 1);
}

// ---------------- multi-block exclusive scan, 3 phases ----------------
__global__ __launch_bounds__(256) void scan_partA(const int* __restrict__ deg,
                                                  int* __restrict__ bsum, int n) {
    __shared__ int red[256];
    int b = blockIdx.x;
    int chunk = (n + SCAN_NB - 1) / SCAN_NB;
    int s0 = b * chunk, s1 = min(s0 + chunk, n);
    int sum = 0;
    for (int i = s0 + threadIdx.x; i < s1; i += 256) sum += deg[i];
    red[threadIdx.x] = sum;
    __syncthreads();
    for (int off = 128; off >= 1; off >>= 1) {
        if (threadIdx.x < off) red[threadIdx.x] += red[threadIdx.x + off];
        __syncthreads();
    }
    if (threadIdx.x == 0) bsum[b] = red[0];
}

__global__ __launch_bounds__(SCAN_NB) void scan_partB(const int* __restrict__ bsum,
                                                      int* __restrict__ boff,
                                                      int* __restrict__ offs, int n) {
    __shared__ int tmp[SCAN_NB];
    int tid = threadIdx.x;
    int v = bsum[tid];
    tmp[tid] = v;
    __syncthreads();
    for (int off = 1; off < SCAN_NB; off <<= 1) {
        int t = (tid >= off) ? tmp[tid - off] : 0;
        __syncthreads();
        tmp[tid] += t;
        __syncthreads();
    }
    boff[tid] = tmp[tid] - v;
    if (tid == SCAN_NB - 1) offs[n] = tmp[tid];
}

__global__ __launch_bounds__(256) void scan_partC(const int* __restrict__ deg,
                                                  const int* __restrict__ boff,
                                                  int* __restrict__ offs,
                                                  int* __restrict__ cursor, int n) {
    __shared__ int tsum[256];
    int b = blockIdx.x;
    int chunk = (n + SCAN_NB - 1) / SCAN_NB;
    int s0 = b * chunk, s1 = min(s0 + chunk, n);
    int tchunk = (chunk + 255) >> 8;
    int t0 = s0 + threadIdx.x * tchunk;
    int t1 = min(t0 + tchunk, s1);
    int sum = 0;
    for (int i = t0; i < t1; ++i) sum += deg[i];
    tsum[threadIdx.x] = sum;
    __syncthreads();
    for (int off = 1; off < 256; off <<= 1) {
        int t = (threadIdx.x >= off) ? tsum[threadIdx.x - off] : 0;
        __syncthreads();
        tsum[threadIdx.x] += t;
        __syncthreads();
    }
    int run = boff[b] + tsum[threadIdx.x] - sum;
    for (int i = t0; i < t1; ++i) {
        offs[i] = run; cursor[i] = run; run += deg[i];
    }
}

// ---------------- binned CSR fill ----------------
// bucket cursors start at offs[bucket_first_node]
__global__ void bin_init(const int* __restrict__ offs, int* __restrict__ bcur, int nb) {
    int b = blockIdx.x * blockDim.x + threadIdx.x;
    if (b < nb) bcur[b] = offs[b << 8];   // b*NPB
}

// Phase 1: bucket the edges. staged[pos] = (dstLocal<<24) | src  (needs n_nodes < 2^24)
__global__ __launch_bounds__(256) void bin_kernel(const int* __restrict__ ei,
                                                  int* __restrict__ bcur,
                                                  unsigned int* __restrict__ staged,
                                                  int n_edges, int nb) {
    __shared__ int hist[MAXNB];
    __shared__ int base[MAXNB];
    int tid = threadIdx.x;
    for (int i = tid; i < nb; i += 256) hist[i] = 0;
    __syncthreads();
    int chunk = (n_edges + gridDim.x - 1) / gridDim.x;
    int e0 = blockIdx.x * chunk, e1 = min(e0 + chunk, n_edges);
    const int* dstp = ei + n_edges;
    for (int e = e0 + tid; e < e1; e += 256)
        atomicAdd(&hist[dstp[e] >> 8], 1);
    __syncthreads();
    for (int i = tid; i < nb; i += 256) {
        int c = hist[i];
        base[i] = c ? atomicAdd(&bcur[i], c) : 0;
        hist[i] = 0;                      // reuse as run cursor
    }
    __syncthreads();
    for (int e = e0 + tid; e < e1; e += 256) {
        int dst = dstp[e];
        int b = dst >> 8;
        int pos = base[b] + atomicAdd(&hist[b], 1);
        staged[pos] = ((unsigned int)(dst & 255) << 24) | (unsigned int)ei[e];
    }
}

// Phase 2: one block per bucket; LDS cursors; csr writes stay in one L2-hot window.
__global__ __launch_bounds__(256) void fill2_kernel(const unsigned int* __restrict__ staged,
                                                    const int* __restrict__ offs,
                                                    int* __restrict__ csr, int n_nodes) {
    __shared__ int cur[NPB];
    int b = blockIdx.x;
    int n0 = b << 8;
    int n1 = min(n0 + NPB, n_nodes);
    int tid = threadIdx.x;
    for (int i = tid; i < n1 - n0; i += 256) cur[i] = offs[n0 + i];
    __syncthreads();
    int e0 = offs[n0], e1 = offs[n1];
    for (int e = e0 + tid; e < e1; e += 256) {
        unsigned int u = staged[e];
        int dl = u >> 24;
        int pos = atomicAdd(&cur[dl], 1);
        csr[pos] = (int)(u & 0xFFFFFFu);
    }
}

// ---------------- legacy single-pass fill (fallback paths) ----------------
__global__ void fill_kernel(const int* __restrict__ ei, int* __restrict__ cursor,
                            int* __restrict__ csr, int n_edges) {
    for (int e = blockIdx.x * blockDim.x + threadIdx.x; e < n_edges;
         e += gridDim.x * blockDim.x) {
        int src = ei[e];
        int dst = ei[n_edges + e];
        int pos = atomicAdd(&cursor[dst], 1);
        csr[pos] = src;
    }
}

// ---------------- per-node gather + mean (wave per node) ----------------
template <int XBSRC, int BF16OUT>
__global__ void gather_kernel(const void* __restrict__ xsrc,
                              const int* __restrict__ offs,
                              const int* __restrict__ csr,
                              void* __restrict__ agg, int n_nodes) {
    int lane = threadIdx.x & 63;
    int gw = (blockIdx.x * blockDim.x + threadIdx.x) >> 6;
    int nw = (gridDim.x * blockDim.x) >> 6;
    for (int node = gw; node < n_nodes; node += nw) {
        int o0 = offs[node], o1 = offs[node + 1];
        float ax = 0.0f, ay = 0.0f;
        if (XBSRC) {
            const unsigned int* xu = (const unsigned int*)xsrc;
            int i = o0;
            for (; i + 1 < o1; i += 2) {
                int s0 = csr[i], s1 = csr[i + 1];
                unsigned int u0 = xu[(size_t)s0 * 64 + lane];
                unsigned int u1 = xu[(size_t)s1 * 64 + lane];
                ax += bf_lo(u0); ay += bf_hi(u0);
                ax += bf_lo(u1); ay += bf_hi(u1);
            }
            if (i < o1) {
                unsigned int u0 = xu[(size_t)csr[i] * 64 + lane];
                ax += bf_lo(u0); ay += bf_hi(u0);
            }
        } else {
            const float* xf = (const float*)xsrc;
            for (int i = o0; i < o1; ++i) {
                int src = csr[i];
                float2 v = reinterpret_cast<const float2*>(xf)[(size_t)src * 64 + lane];
                ax += v.x; ay += v.y;
            }
        }
        float inv = 1.0f / fmaxf((float)(o1 - o0), 1.0f);
        ax *= inv; ay *= inv;
        if (BF16OUT) {
            unsigned int p = (unsigned int)f2bf(ax) | ((unsigned int)f2bf(ay) << 16);
            reinterpret_cast<unsigned int*>(agg)[(size_t)node * 64 + lane] = p;
        } else {
            float2 r; r.x = ax; r.y = ay;
            reinterpret_cast<float2*>(agg)[(size_t)node * 64 + lane] = r;
        }
    }
}

// ---------------- fused MFMA SAGEConv + LayerNorm + ReLU ----------------
template <int AGG_BF16, int XB16>
__global__ __launch_bounds__(256) void sage_mfma(
        const void* __restrict__ xsrc,
        const void* __restrict__ aggv,
        const float* __restrict__ Wl,
        const float* __restrict__ bl,
        const float* __restrict__ Wr,
        const float* __restrict__ gamma,
        const float* __restrict__ beta,
        float* __restrict__ out,
        int n_nodes) {
    __shared__ short wfrag[8 * 8 * 64 * 8];   // [n0][kk][lane][8] bf16 = 64KB

    int tid = threadIdx.x;
    for (int e = tid; e < 32768; e += 256) {
        int j = e & 7, lane_ = (e >> 3) & 63, kk = (e >> 9) & 7, n0 = e >> 12;
        int dd = n0 * 16 + (lane_ & 15);
        int k = kk * 32 + 8 * (lane_ >> 4) + j;
        float w = (k < 128) ? Wl[dd * 128 + k] : Wr[dd * 128 + (k - 128)];
        wfrag[e] = (short)f2bf(w);
    }
    __syncthreads();

    int wave = tid >> 6, lane = tid & 63;
    int sl = lane & 15, g = lane >> 4;
    int gw = blockIdx.x * 4 + wave;
    int nw = gridDim.x * 4;
    int ntiles = (n_nodes + 15) >> 4;

    float blv[8], gmv[8], btv[8];
    #pragma unroll
    for (int n0 = 0; n0 < 8; ++n0) {
        blv[n0] = bl[n0 * 16 + sl];
        gmv[n0] = gamma[n0 * 16 + sl];
        btv[n0] = beta[n0 * 16 + sl];
    }

    const bf16x8* wf = reinterpret_cast<const bf16x8*>(wfrag);

    for (int t = gw; t < ntiles; t += nw) {
        int R0 = t << 4;
        int node = R0 + sl;
        if (node >= n_nodes) node = n_nodes - 1;

        bf16x8 va[8];
        if (AGG_BF16) {
            const bf16x8* ar = reinterpret_cast<const bf16x8*>(aggv) + (size_t)node * 16;
            #pragma unroll
            for (int kk = 0; kk < 4; ++kk) va[kk] = ar[kk * 4 + g];
        } else {
            const float* ar = reinterpret_cast<const float*>(aggv) + (size_t)node * 128;
            #pragma unroll
            for (int kk = 0; kk < 4; ++kk) {
                int base = kk * 32 + 8 * g;
                float4 u0 = *reinterpret_cast<const float4*>(ar + base);
                float4 u1 = *reinterpret_cast<const float4*>(ar + base + 4);
                bf16x8 v;
                v[0] = (short)f2bf(u0.x); v[1] = (short)f2bf(u0.y);
                v[2] = (short)f2bf(u0.z); v[3] = (short)f2bf(u0.w);
                v[4] = (short)f2bf(u1.x); v[5] = (short)f2bf(u1.y);
                v[6] = (short)f2bf(u1.z); v[7] = (short)f2bf(u1.w);
                va[kk] = v;
            }
        }
        if (XB16) {
            const bf16x8* xr = reinterpret_cast<const bf16x8*>(xsrc) + (size_t)node * 16;
            #pragma unroll
            for (int kk = 0; kk < 4; ++kk) va[4 + kk] = xr[kk * 4 + g];
        } else {
            const float* xr = reinterpret_cast<const float*>(xsrc) + (size_t)node * 128;
            #pragma unroll
            for (int kk = 0; kk < 4; ++kk) {
                int base = kk * 32 + 8 * g;
                float4 u0 = *reinterpret_cast<const float4*>(xr + base);
                float4 u1 = *reinterpret_cast<const float4*>(xr + base + 4);
                bf16x8 v;
                v[0] = (short)f2bf(u0.x); v[1] = (short)f2bf(u0.y);
                v[2] = (short)f2bf(u0.z); v[3] = (short)f2bf(u0.w);
                v[4] = (short)f2bf(u1.x); v[5] = (short)f2bf(u1.y);
                v[6] = (short)f2bf(u1.z); v[7] = (short)f2bf(u1.w);
                va[4 + kk] = v;
            }
        }

        f32x4 acc[8];
        #pragma unroll
        for (int n0 = 0; n0 < 8; ++n0) acc[n0] = (f32x4){0.f, 0.f, 0.f, 0.f};

        #pragma unroll
        for (int n0 = 0; n0 < 8; ++n0)
            #pragma unroll
            for (int kk = 0; kk < 8; ++kk)
                acc[n0] = __builtin_amdgcn_mfma_f32_16x16x32_bf16(
                    va[kk], wf[(n0 * 8 + kk) * 64 + lane], acc[n0], 0, 0, 0);

        float s[4] = {0.f, 0.f, 0.f, 0.f}, sq[4] = {0.f, 0.f, 0.f, 0.f};
        #pragma unroll
        for (int n0 = 0; n0 < 8; ++n0) {
            #pragma unroll
            for (int r = 0; r < 4; ++r) {
                float v = acc[n0][r] + blv[n0];
                acc[n0][r] = v;
                s[r] += v; sq[r] += v * v;
            }
        }
        #pragma unroll
        for (int off = 1; off <= 8; off <<= 1) {
            #pragma unroll
            for (int r = 0; r < 4; ++r) {
                s[r]  += __shfl_xor(s[r], off, 64);
                sq[r] += __shfl_xor(sq[r], off, 64);
            }
        }
        float mu[4], rstd[4];
        #pragma unroll
        for (int r = 0; r < 4; ++r) {
            mu[r] = s[r] * (1.0f / 128.0f);
            float var = sq[r] * (1.0f / 128.0f) - mu[r] * mu[r];
            rstd[r] = rsqrtf(var + 1e-5f);
        }
        #pragma unroll
        for (int n0 = 0; n0 < 8; ++n0) {
            #pragma unroll
            for (int r = 0; r < 4; ++r) {
                int m = R0 + 4 * g + r;
                if (m < n_nodes) {
                    float o = (acc[n0][r] - mu[r]) * rstd[r] * gmv[n0] + btv[n0];
                    out[(size_t)m * 128 + n0 * 16 + sl] = fmaxf(o, 0.0f);
                }
            }
        }
    }
}

// ---------------- deep fallback (atomic scatter + scalar sage) ----------------
__global__ void zero_f(float* __restrict__ a, float* __restrict__ dg, int n_nodes) {
    int total = n_nodes * D + n_nodes;
    for (int i = blockIdx.x * blockDim.x + threadIdx.x; i < total;
         i += gridDim.x * blockDim.x) {
        if (i < n_nodes * D) a[i] = 0.0f;
        else                 dg[i - n_nodes * D] = 0.0f;
    }
}
__global__ void scatter_kernel(const float* __restrict__ x, const int* __restrict__ ei,
                               float* __restrict__ agg, float* __restrict__ deg, int n_edges) {
    long long total = (long long)n_edges * 32;
    for (long long idx = blockIdx.x * (long long)blockDim.x + threadIdx.x; idx < total;
         idx += (long long)gridDim.x * blockDim.x) {
        int e = (int)(idx >> 5);
        int j = (int)(idx & 31);
        int src = ei[e];
        int dst = ei[n_edges + e];
        float4 v = reinterpret_cast<const float4*>(x)[(long long)src * 32 + j];
        float* a = agg + (long long)dst * D + j * 4;
        atomicAdd(a + 0, v.x); atomicAdd(a + 1, v.y);
        atomicAdd(a + 2, v.z); atomicAdd(a + 3, v.w);
        if (j == 0) atomicAdd(deg + dst, 1.0f);
    }
}
__global__ __launch_bounds__(1024) void sage_scalar(
        const float* __restrict__ x, const float* __restrict__ agg_in,
        const float* __restrict__ deg,
        const float* __restrict__ Wl, const float* __restrict__ bl,
        const float* __restrict__ Wr,
        const float* __restrict__ gamma, const float* __restrict__ beta,
        float* __restrict__ out, int n_nodes) {
    __shared__ float wlt[128 * 129];
    __shared__ float wrt[128 * 129];
    __shared__ float rows[16][256];
    int tid = threadIdx.x;
    for (int i = tid; i < 128 * 128; i += 1024) {
        int d = i >> 7, k = i & 127;
        wlt[k * 129 + d] = Wl[i];
        wrt[k * 129 + d] = Wr[i];
    }
    __syncthreads();
    int wave = tid >> 6, lane = tid & 63;
    int gwave = blockIdx.x * 16 + wave;
    int nwaves = gridDim.x * 16;
    float* row = rows[wave];
    int d0 = lane, d1 = lane + 64;
    float bl0 = bl[d0], bl1 = bl[d1];
    float g0 = gamma[d0], g1 = gamma[d1];
    float be0 = beta[d0], be1 = beta[d1];
    for (int n = gwave; n < n_nodes; n += nwaves) {
        float inv = 1.0f / fmaxf(deg[n], 1.0f);
        long long base = (long long)n * D;
        row[lane]       = agg_in[base + lane] * inv;
        row[lane + 64]  = agg_in[base + lane + 64] * inv;
        row[lane + 128] = x[base + lane];
        row[lane + 192] = x[base + lane + 64];
        float acc0 = bl0, acc1 = bl1;
        #pragma unroll 4
        for (int k = 0; k < 128; ++k) {
            float a  = row[k];
            float xv = row[128 + k];
            acc0 += a * wlt[k * 129 + d0];
            acc1 += a * wlt[k * 129 + d1];
            acc0 += xv * wrt[k * 129 + d0];
            acc1 += xv * wrt[k * 129 + d1];
        }
        float s  = acc0 + acc1;
        float sq = acc0 * acc0 + acc1 * acc1;
        #pragma unroll
        for (int off = 32; off >= 1; off >>= 1) {
            s  += __shfl_xor(s, off, 64);
            sq += __shfl_xor(sq, off, 64);
        }
        float mu = s * (1.0f / 128.0f);
        float var = sq * (1.0f / 128.0f) - mu * mu;
        float rstd = rsqrtf(var + 1e-5f);
        float o0 = (acc0 - mu) * rstd * g0 + be0;
        float o1 = (acc1 - mu) * rstd * g1 + be1;
        out[base + d0] = fmaxf(o0, 0.0f);
        out[base + d1] = fmaxf(o1, 0.0f);
    }
}

extern "C" void kernel_launch(void* const* d_in, const int* in_sizes, int n_in,
                              void* d_out, int out_size, void* d_ws, size_t ws_size,
                              hipStream_t stream) {
    const float* x     = (const float*)d_in[0];
    const int*   ei    = (const int*)d_in[1];
    const float* Wl    = (const float*)d_in[2];
    const float* bl    = (const float*)d_in[3];
    const float* Wr    = (const float*)d_in[4];
    const float* gamma = (const float*)d_in[5];
    const float* beta  = (const float*)d_in[6];

    int n_nodes = in_sizes[0] / D;
    int n_edges = in_sizes[1] / 2;
    int nb = (n_nodes + NPB - 1) / NPB;

    // ws layout: deg[N] | offs[N+1] | cursor[N] | bsum | boff | csr[E] (ints)
    //            | [256-aligned] agg_bf16[N*128] | xb_bf16[N*128]
    // staged (E u32) aliases the agg region (dead before gather writes agg).
    size_t int_elems = (size_t)n_nodes * 3 + 1 + 2 * SCAN_NB + (size_t)n_edges;
    size_t int_bytes = int_elems * sizeof(int);
    size_t aggb_off  = (int_bytes + 255) & ~(size_t)255;
    size_t xb_off    = aggb_off + (size_t)n_nodes * 128 * 2;
    size_t need_full = xb_off + (size_t)n_nodes * 128 * 2;
    size_t need_a    = xb_off;
    size_t need_b    = int_bytes;

    if (ws_size >= need_b) {
        int* deg    = (int*)d_ws;
        int* offs   = deg + n_nodes;
        int* cursor = offs + n_nodes + 1;
        int* bsum   = cursor + n_nodes;
        int* boff   = bsum + SCAN_NB;
        int* csr    = boff + SCAN_NB;

        hipMemsetAsync(deg, 0, (size_t)n_nodes * sizeof(int), stream);
        count_kernel<<<2048, 256, 0, stream>>>(ei, deg, n_edges);
        scan_partA<<<SCAN_NB, 256, 0, stream>>>(deg, bsum, n_nodes);
        scan_partB<<<1, SCAN_NB, 0, stream>>>(bsum, boff, offs, n_nodes);
        scan_partC<<<SCAN_NB, 256, 0, stream>>>(deg, boff, offs, cursor, n_nodes);

        bool binnable = (nb <= MAXNB) && (n_nodes < (1 << 24)) &&
                        ((size_t)n_edges * 4 <= (size_t)n_nodes * 128 * 2);

        if (ws_size >= need_full) {
            void* aggb = (char*)d_ws + aggb_off;
            unsigned int* xb = (unsigned int*)((char*)d_ws + xb_off);

            if (binnable) {
                unsigned int* staged = (unsigned int*)aggb;   // alias: dead before gather
                bin_init<<<(nb + 255) / 256, 256, 0, stream>>>(offs, cursor, nb);
                bin_kernel<<<256, 256, 0, stream>>>(ei, cursor, staged, n_edges, nb);
                fill2_kernel<<<nb, 256, 0, stream>>>(staged, offs, csr, n_nodes);
            } else {
                fill_kernel<<<2048, 256, 0, stream>>>(ei, cursor, csr, n_edges);
            }
            long long n4 = (long long)n_nodes * 32;
            convert_kernel<<<2048, 256, 0, stream>>>(x, xb, n4);
            gather_kernel<1, 1><<<2048, 256, 0, stream>>>(xb, offs, csr, aggb, n_nodes);
            sage_mfma<1, 1><<<512, 256, 0, stream>>>(xb, aggb, Wl, bl, Wr, gamma, beta,
                                                     (float*)d_out, n_nodes);
        } else if (ws_size >= need_a) {
            void* aggb = (char*)d_ws + aggb_off;
            fill_kernel<<<2048, 256, 0, stream>>>(ei, cursor, csr, n_edges);
            gather_kernel<0, 1><<<2048, 256, 0, stream>>>(x, offs, csr, aggb, n_nodes);
            sage_mfma<1, 0><<<512, 256, 0, stream>>>(x, aggb, Wl, bl, Wr, gamma, beta,
                                                     (float*)d_out, n_nodes);
        } else {
            float* aggf = (float*)d_out;
            fill_kernel<<<2048, 256, 0, stream>>>(ei, cursor, csr, n_edges);
            gather_kernel<0, 0><<<2048, 256, 0, stream>>>(x, offs, csr, aggf, n_nodes);
            sage_mfma<0, 0><<<512, 256, 0, stream>>>(x, aggf, Wl, bl, Wr, gamma, beta,
                                                     (float*)d_out, n_nodes);
        }
    } else {
        float* degf = (float*)d_ws;
        zero_f<<<2048, 256, 0, stream>>>((float*)d_out, degf, n_nodes);
        scatter_kernel<<<2048, 256, 0, stream>>>(x, ei, (float*)d_out, degf, n_edges);
        sage_scalar<<<512, 1024, 0, stream>>>(x, (float*)d_out, degf, Wl, bl, Wr,
                                              gamma, beta, (float*)d_out, n_nodes);
    }
}

// Round 7
// 196.039 us; speedup vs baseline: 16.4181x; 1.4150x over previous
//
#include <hip/hip_runtime.h>

// GraphSAGE block: bf16-convert -> bucketed CSR build -> wide gather mean -> MFMA SAGE+LN+ReLU
// N=100000, E=1600000, D_IN=D_OUT=128

#define D 128
#define SCAN_NB 256   // blocks in legacy multi-block scan (fallback path)
#define NPB 256       // nodes per dst-bucket (dstLocal fits 8 bits)
#define MAXNB 1024    // max buckets (single-block bucket scan)

typedef __attribute__((ext_vector_type(8))) short bf16x8;   // 8 bf16 in 4 VGPRs
typedef __attribute__((ext_vector_type(4))) float f32x4;

__device__ inline unsigned short f2bf(float f) {            // f32 -> bf16 RNE
    unsigned int u = __builtin_bit_cast(unsigned int, f);
    u += 0x7FFFu + ((u >> 16) & 1u);
    return (unsigned short)(u >> 16);
}
__device__ inline float bf_lo(unsigned int u) {
    return __builtin_bit_cast(float, u << 16);
}
__device__ inline float bf_hi(unsigned int u) {
    return __builtin_bit_cast(float, u & 0xFFFF0000u);
}

// ---------------- convert x (f32) -> xb (bf16) ----------------
__global__ void convert_kernel(const float* __restrict__ x,
                               unsigned int* __restrict__ xb2, long long n4) {
    for (long long i = blockIdx.x * (long long)blockDim.x + threadIdx.x; i < n4;
         i += (long long)gridDim.x * blockDim.x) {
        float4 v = reinterpret_cast<const float4*>(x)[i];
        unsigned int lo = (unsigned int)f2bf(v.x) | ((unsigned int)f2bf(v.y) << 16);
        unsigned int hi = (unsigned int)f2bf(v.z) | ((unsigned int)f2bf(v.w) << 16);
        xb2[2 * i]     = lo;
        xb2[2 * i + 1] = hi;
    }
}

// ---------------- bucket-level degree count (LDS hist, few global atomics) ----------------
__global__ __launch_bounds__(256) void bucket_count(const int* __restrict__ ei,
                                                    int* __restrict__ bc,
                                                    int n_edges, int nb) {
    __shared__ int hist[MAXNB];
    int tid = threadIdx.x;
    for (int i = tid; i < nb; i += 256) hist[i] = 0;
    __syncthreads();
    const int* dstp = ei + n_edges;
    for (int e = blockIdx.x * 256 + tid; e < n_edges; e += gridDim.x * 256)
        atomicAdd(&hist[dstp[e] >> 8], 1);
    __syncthreads();
    for (int i = tid; i < nb; i += 256) {
        int c = hist[i];
        if (c) atomicAdd(&bc[i], c);
    }
}

// ---------------- single-block scan of bucket counts -> bbase, bcur; offs[n]=total ----------------
__global__ __launch_bounds__(1024) void bucket_scan(const int* __restrict__ bc,
                                                    int* __restrict__ bbase,
                                                    int* __restrict__ bcur,
                                                    int* __restrict__ offs,
                                                    int nb, int n_nodes) {
    __shared__ int tmp[1024];
    int tid = threadIdx.x;
    int v = (tid < nb) ? bc[tid] : 0;
    tmp[tid] = v;
    __syncthreads();
    for (int off = 1; off < 1024; off <<= 1) {
        int t = (tid >= off) ? tmp[tid - off] : 0;
        __syncthreads();
        tmp[tid] += t;
        __syncthreads();
    }
    if (tid < nb) {
        int excl = tmp[tid] - v;
        bbase[tid] = excl;
        bcur[tid]  = excl;
    }
    if (tid == 1023) {
        bbase[nb] = tmp[1023];
        offs[n_nodes] = tmp[1023];
    }
}

// ---------------- Phase 1: bucket the edges ----------------
// staged[pos] = (dstLocal<<24) | src   (requires n_nodes < 2^24)
__global__ __launch_bounds__(256) void bin_kernel(const int* __restrict__ ei,
                                                  int* __restrict__ bcur,
                                                  unsigned int* __restrict__ staged,
                                                  int n_edges, int nb) {
    __shared__ int hist[MAXNB];
    __shared__ int base[MAXNB];
    int tid = threadIdx.x;
    for (int i = tid; i < nb; i += 256) hist[i] = 0;
    __syncthreads();
    int chunk = (n_edges + gridDim.x - 1) / gridDim.x;
    int e0 = blockIdx.x * chunk, e1 = min(e0 + chunk, n_edges);
    const int* dstp = ei + n_edges;
    for (int e = e0 + tid; e < e1; e += 256)
        atomicAdd(&hist[dstp[e] >> 8], 1);
    __syncthreads();
    for (int i = tid; i < nb; i += 256) {
        int c = hist[i];
        base[i] = c ? atomicAdd(&bcur[i], c) : 0;
        hist[i] = 0;                      // reuse as run cursor
    }
    __syncthreads();
    for (int e = e0 + tid; e < e1; e += 256) {
        int dst = dstp[e];
        int b = dst >> 8;
        int pos = base[b] + atomicAdd(&hist[b], 1);
        staged[pos] = ((unsigned int)(dst & 255) << 24) | (unsigned int)ei[e];
    }
}

// ---------------- Phase 2: per-bucket LDS counting sort -> offs + csr ----------------
__global__ __launch_bounds__(256) void fill2_sort(const unsigned int* __restrict__ staged,
                                                  const int* __restrict__ bbase,
                                                  int* __restrict__ offs,
                                                  int* __restrict__ csr, int n_nodes) {
    __shared__ int hist[NPB];
    __shared__ int scn[NPB];
    int b = blockIdx.x;
    int n0 = b << 8;
    int nn = min(NPB, n_nodes - n0);
    int tid = threadIdx.x;
    int e0 = bbase[b], e1 = bbase[b + 1];

    hist[tid] = 0;
    __syncthreads();
    for (int e = e0 + tid; e < e1; e += 256)
        atomicAdd(&hist[staged[e] >> 24], 1);
    __syncthreads();
    int h = hist[tid];
    scn[tid] = h;
    __syncthreads();
    for (int off = 1; off < 256; off <<= 1) {
        int t = (tid >= off) ? scn[tid - off] : 0;
        __syncthreads();
        scn[tid] += t;
        __syncthreads();
    }
    int start = e0 + scn[tid] - h;        // exclusive prefix + bucket base
    if (tid < nn) offs[n0 + tid] = start;
    scn[tid] = start;                     // reuse as cursor
    __syncthreads();
    for (int e = e0 + tid; e < e1; e += 256) {
        unsigned int u = staged[e];
        int dl = u >> 24;
        int pos = atomicAdd(&scn[dl], 1);
        csr[pos] = (int)(u & 0xFFFFFFu);
    }
}

// ---------------- wide gather: uint4/lane, 4 rows per VMEM instr, unroll 2 ----------------
__global__ void gather4_kernel(const unsigned int* __restrict__ xu,
                               const int* __restrict__ offs,
                               const int* __restrict__ csr,
                               unsigned int* __restrict__ agg, int n_nodes) {
    int lane = threadIdx.x & 63;
    int col = lane & 15;       // uint4 index within the row (features 8*col..8*col+7)
    int q   = lane >> 4;       // quarter: which edge of a group of 4
    int gw = (blockIdx.x * blockDim.x + threadIdx.x) >> 6;
    int nw = (gridDim.x * blockDim.x) >> 6;

    for (int node = gw; node < n_nodes; node += nw) {
        int o0 = offs[node], o1 = offs[node + 1];
        float a0 = 0.f, a1 = 0.f, a2 = 0.f, a3 = 0.f,
              a4 = 0.f, a5 = 0.f, a6 = 0.f, a7 = 0.f;
        int i = o0 + q;
        #define ACC(u) do { \
            a0 += bf_lo((u).x); a1 += bf_hi((u).x); \
            a2 += bf_lo((u).y); a3 += bf_hi((u).y); \
            a4 += bf_lo((u).z); a5 += bf_hi((u).z); \
            a6 += bf_lo((u).w); a7 += bf_hi((u).w); } while (0)
        for (; i + 4 < o1; i += 8) {
            int s0 = csr[i], s1 = csr[i + 4];
            uint4 u0 = *reinterpret_cast<const uint4*>(xu + (size_t)s0 * 64 + (col << 2));
            uint4 u1 = *reinterpret_cast<const uint4*>(xu + (size_t)s1 * 64 + (col << 2));
            ACC(u0); ACC(u1);
        }
        for (; i < o1; i += 4) {
            int s0 = csr[i];
            uint4 u0 = *reinterpret_cast<const uint4*>(xu + (size_t)s0 * 64 + (col << 2));
            ACC(u0);
        }
        #undef ACC
        // combine quarters (each handled a disjoint subset of edges)
        a0 += __shfl_xor(a0, 16, 64); a0 += __shfl_xor(a0, 32, 64);
        a1 += __shfl_xor(a1, 16, 64); a1 += __shfl_xor(a1, 32, 64);
        a2 += __shfl_xor(a2, 16, 64); a2 += __shfl_xor(a2, 32, 64);
        a3 += __shfl_xor(a3, 16, 64); a3 += __shfl_xor(a3, 32, 64);
        a4 += __shfl_xor(a4, 16, 64); a4 += __shfl_xor(a4, 32, 64);
        a5 += __shfl_xor(a5, 16, 64); a5 += __shfl_xor(a5, 32, 64);
        a6 += __shfl_xor(a6, 16, 64); a6 += __shfl_xor(a6, 32, 64);
        a7 += __shfl_xor(a7, 16, 64); a7 += __shfl_xor(a7, 32, 64);
        if (q == 0) {
            float inv = 1.0f / fmaxf((float)(o1 - o0), 1.0f);
            uint4 p;
            p.x = (unsigned int)f2bf(a0 * inv) | ((unsigned int)f2bf(a1 * inv) << 16);
            p.y = (unsigned int)f2bf(a2 * inv) | ((unsigned int)f2bf(a3 * inv) << 16);
            p.z = (unsigned int)f2bf(a4 * inv) | ((unsigned int)f2bf(a5 * inv) << 16);
            p.w = (unsigned int)f2bf(a6 * inv) | ((unsigned int)f2bf(a7 * inv) << 16);
            *reinterpret_cast<uint4*>(agg + (size_t)node * 64 + (col << 2)) = p;
        }
    }
}

// ================= legacy kernels for fallback paths =================
__global__ void count_kernel(const int* __restrict__ ei, int* __restrict__ deg, int n_edges) {
    for (int e = blockIdx.x * blockDim.x + threadIdx.x; e < n_edges;
         e += gridDim.x * blockDim.x)
        atomicAdd(&deg[ei[n_edges + e]], 1);
}
__global__ __launch_bounds__(256) void scan_partA(const int* __restrict__ deg,
                                                  int* __restrict__ bsum, int n) {
    __shared__ int red[256];
    int b = blockIdx.x;
    int chunk = (n + SCAN_NB - 1) / SCAN_NB;
    int s0 = b * chunk, s1 = min(s0 + chunk, n);
    int sum = 0;
    for (int i = s0 + threadIdx.x; i < s1; i += 256) sum += deg[i];
    red[threadIdx.x] = sum;
    __syncthreads();
    for (int off = 128; off >= 1; off >>= 1) {
        if (threadIdx.x < off) red[threadIdx.x] += red[threadIdx.x + off];
        __syncthreads();
    }
    if (threadIdx.x == 0) bsum[b] = red[0];
}
__global__ __launch_bounds__(SCAN_NB) void scan_partB(const int* __restrict__ bsum,
                                                      int* __restrict__ boff,
                                                      int* __restrict__ offs, int n) {
    __shared__ int tmp[SCAN_NB];
    int tid = threadIdx.x;
    int v = bsum[tid];
    tmp[tid] = v;
    __syncthreads();
    for (int off = 1; off < SCAN_NB; off <<= 1) {
        int t = (tid >= off) ? tmp[tid - off] : 0;
        __syncthreads();
        tmp[tid] += t;
        __syncthreads();
    }
    boff[tid] = tmp[tid] - v;
    if (tid == SCAN_NB - 1) offs[n] = tmp[tid];
}
__global__ __launch_bounds__(256) void scan_partC(const int* __restrict__ deg,
                                                  const int* __restrict__ boff,
                                                  int* __restrict__ offs,
                                                  int* __restrict__ cursor, int n) {
    __shared__ int tsum[256];
    int b = blockIdx.x;
    int chunk = (n + SCAN_NB - 1) / SCAN_NB;
    int s0 = b * chunk, s1 = min(s0 + chunk, n);
    int tchunk = (chunk + 255) >> 8;
    int t0 = s0 + threadIdx.x * tchunk;
    int t1 = min(t0 + tchunk, s1);
    int sum = 0;
    for (int i = t0; i < t1; ++i) sum += deg[i];
    tsum[threadIdx.x] = sum;
    __syncthreads();
    for (int off = 1; off < 256; off <<= 1) {
        int t = (threadIdx.x >= off) ? tsum[threadIdx.x - off] : 0;
        __syncthreads();
        tsum[threadIdx.x] += t;
        __syncthreads();
    }
    int run = boff[b] + tsum[threadIdx.x] - sum;
    for (int i = t0; i < t1; ++i) {
        offs[i] = run; cursor[i] = run; run += deg[i];
    }
}
__global__ void fill_kernel(const int* __restrict__ ei, int* __restrict__ cursor,
                            int* __restrict__ csr, int n_edges) {
    for (int e = blockIdx.x * blockDim.x + threadIdx.x; e < n_edges;
         e += gridDim.x * blockDim.x) {
        int src = ei[e];
        int dst = ei[n_edges + e];
        int pos = atomicAdd(&cursor[dst], 1);
        csr[pos] = src;
    }
}
template <int XBSRC, int BF16OUT>
__global__ void gather_kernel(const void* __restrict__ xsrc,
                              const int* __restrict__ offs,
                              const int* __restrict__ csr,
                              void* __restrict__ agg, int n_nodes) {
    int lane = threadIdx.x & 63;
    int gw = (blockIdx.x * blockDim.x + threadIdx.x) >> 6;
    int nw = (gridDim.x * blockDim.x) >> 6;
    for (int node = gw; node < n_nodes; node += nw) {
        int o0 = offs[node], o1 = offs[node + 1];
        float ax = 0.0f, ay = 0.0f;
        if (XBSRC) {
            const unsigned int* xu = (const unsigned int*)xsrc;
            for (int i = o0; i < o1; ++i) {
                unsigned int u0 = xu[(size_t)csr[i] * 64 + lane];
                ax += bf_lo(u0); ay += bf_hi(u0);
            }
        } else {
            const float* xf = (const float*)xsrc;
            for (int i = o0; i < o1; ++i) {
                float2 v = reinterpret_cast<const float2*>(xf)[(size_t)csr[i] * 64 + lane];
                ax += v.x; ay += v.y;
            }
        }
        float inv = 1.0f / fmaxf((float)(o1 - o0), 1.0f);
        ax *= inv; ay *= inv;
        if (BF16OUT) {
            unsigned int p = (unsigned int)f2bf(ax) | ((unsigned int)f2bf(ay) << 16);
            reinterpret_cast<unsigned int*>(agg)[(size_t)node * 64 + lane] = p;
        } else {
            float2 r; r.x = ax; r.y = ay;
            reinterpret_cast<float2*>(agg)[(size_t)node * 64 + lane] = r;
        }
    }
}

// ---------------- fused MFMA SAGEConv + LayerNorm + ReLU ----------------
template <int AGG_BF16, int XB16>
__global__ __launch_bounds__(256) void sage_mfma(
        const void* __restrict__ xsrc,
        const void* __restrict__ aggv,
        const float* __restrict__ Wl,
        const float* __restrict__ bl,
        const float* __restrict__ Wr,
        const float* __restrict__ gamma,
        const float* __restrict__ beta,
        float* __restrict__ out,
        int n_nodes) {
    __shared__ short wfrag[8 * 8 * 64 * 8];   // [n0][kk][lane][8] bf16 = 64KB

    int tid = threadIdx.x;
    for (int e = tid; e < 32768; e += 256) {
        int j = e & 7, lane_ = (e >> 3) & 63, kk = (e >> 9) & 7, n0 = e >> 12;
        int dd = n0 * 16 + (lane_ & 15);
        int k = kk * 32 + 8 * (lane_ >> 4) + j;
        float w = (k < 128) ? Wl[dd * 128 + k] : Wr[dd * 128 + (k - 128)];
        wfrag[e] = (short)f2bf(w);
    }
    __syncthreads();

    int wave = tid >> 6, lane = tid & 63;
    int sl = lane & 15, g = lane >> 4;
    int gw = blockIdx.x * 4 + wave;
    int nw = gridDim.x * 4;
    int ntiles = (n_nodes + 15) >> 4;

    float blv[8], gmv[8], btv[8];
    #pragma unroll
    for (int n0 = 0; n0 < 8; ++n0) {
        blv[n0] = bl[n0 * 16 + sl];
        gmv[n0] = gamma[n0 * 16 + sl];
        btv[n0] = beta[n0 * 16 + sl];
    }

    const bf16x8* wf = reinterpret_cast<const bf16x8*>(wfrag);

    for (int t = gw; t < ntiles; t += nw) {
        int R0 = t << 4;
        int node = R0 + sl;
        if (node >= n_nodes) node = n_nodes - 1;

        bf16x8 va[8];
        if (AGG_BF16) {
            const bf16x8* ar = reinterpret_cast<const bf16x8*>(aggv) + (size_t)node * 16;
            #pragma unroll
            for (int kk = 0; kk < 4; ++kk) va[kk] = ar[kk * 4 + g];
        } else {
            const float* ar = reinterpret_cast<const float*>(aggv) + (size_t)node * 128;
            #pragma unroll
            for (int kk = 0; kk < 4; ++kk) {
                int base = kk * 32 + 8 * g;
                float4 u0 = *reinterpret_cast<const float4*>(ar + base);
                float4 u1 = *reinterpret_cast<const float4*>(ar + base + 4);
                bf16x8 v;
                v[0] = (short)f2bf(u0.x); v[1] = (short)f2bf(u0.y);
                v[2] = (short)f2bf(u0.z); v[3] = (short)f2bf(u0.w);
                v[4] = (short)f2bf(u1.x); v[5] = (short)f2bf(u1.y);
                v[6] = (short)f2bf(u1.z); v[7] = (short)f2bf(u1.w);
                va[kk] = v;
            }
        }
        if (XB16) {
            const bf16x8* xr = reinterpret_cast<const bf16x8*>(xsrc) + (size_t)node * 16;
            #pragma unroll
            for (int kk = 0; kk < 4; ++kk) va[4 + kk] = xr[kk * 4 + g];
        } else {
            const float* xr = reinterpret_cast<const float*>(xsrc) + (size_t)node * 128;
            #pragma unroll
            for (int kk = 0; kk < 4; ++kk) {
                int base = kk * 32 + 8 * g;
                float4 u0 = *reinterpret_cast<const float4*>(xr + base);
                float4 u1 = *reinterpret_cast<const float4*>(xr + base + 4);
                bf16x8 v;
                v[0] = (short)f2bf(u0.x); v[1] = (short)f2bf(u0.y);
                v[2] = (short)f2bf(u0.z); v[3] = (short)f2bf(u0.w);
                v[4] = (short)f2bf(u1.x); v[5] = (short)f2bf(u1.y);
                v[6] = (short)f2bf(u1.z); v[7] = (short)f2bf(u1.w);
                va[4 + kk] = v;
            }
        }

        f32x4 acc[8];
        #pragma unroll
        for (int n0 = 0; n0 < 8; ++n0) acc[n0] = (f32x4){0.f, 0.f, 0.f, 0.f};

        #pragma unroll
        for (int n0 = 0; n0 < 8; ++n0)
            #pragma unroll
            for (int kk = 0; kk < 8; ++kk)
                acc[n0] = __builtin_amdgcn_mfma_f32_16x16x32_bf16(
                    va[kk], wf[(n0 * 8 + kk) * 64 + lane], acc[n0], 0, 0, 0);

        float s[4] = {0.f, 0.f, 0.f, 0.f}, sq[4] = {0.f, 0.f, 0.f, 0.f};
        #pragma unroll
        for (int n0 = 0; n0 < 8; ++n0) {
            #pragma unroll
            for (int r = 0; r < 4; ++r) {
                float v = acc[n0][r] + blv[n0];
                acc[n0][r] = v;
                s[r] += v; sq[r] += v * v;
            }
        }
        #pragma unroll
        for (int off = 1; off <= 8; off <<= 1) {
            #pragma unroll
            for (int r = 0; r < 4; ++r) {
                s[r]  += __shfl_xor(s[r], off, 64);
                sq[r] += __shfl_xor(sq[r], off, 64);
            }
        }
        float mu[4], rstd[4];
        #pragma unroll
        for (int r = 0; r < 4; ++r) {
            mu[r] = s[r] * (1.0f / 128.0f);
            float var = sq[r] * (1.0f / 128.0f) - mu[r] * mu[r];
            rstd[r] = rsqrtf(var + 1e-5f);
        }
        #pragma unroll
        for (int n0 = 0; n0 < 8; ++n0) {
            #pragma unroll
            for (int r = 0; r < 4; ++r) {
                int m = R0 + 4 * g + r;
                if (m < n_nodes) {
                    float o = (acc[n0][r] - mu[r]) * rstd[r] * gmv[n0] + btv[n0];
                    out[(size_t)m * 128 + n0 * 16 + sl] = fmaxf(o, 0.0f);
                }
            }
        }
    }
}

// ---------------- deep fallback (atomic scatter + scalar sage) ----------------
__global__ void zero_f(float* __restrict__ a, float* __restrict__ dg, int n_nodes) {
    int total = n_nodes * D + n_nodes;
    for (int i = blockIdx.x * blockDim.x + threadIdx.x; i < total;
         i += gridDim.x * blockDim.x) {
        if (i < n_nodes * D) a[i] = 0.0f;
        else                 dg[i - n_nodes * D] = 0.0f;
    }
}
__global__ void scatter_kernel(const float* __restrict__ x, const int* __restrict__ ei,
                               float* __restrict__ agg, float* __restrict__ deg, int n_edges) {
    long long total = (long long)n_edges * 32;
    for (long long idx = blockIdx.x * (long long)blockDim.x + threadIdx.x; idx < total;
         idx += (long long)gridDim.x * blockDim.x) {
        int e = (int)(idx >> 5);
        int j = (int)(idx & 31);
        int src = ei[e];
        int dst = ei[n_edges + e];
        float4 v = reinterpret_cast<const float4*>(x)[(long long)src * 32 + j];
        float* a = agg + (long long)dst * D + j * 4;
        atomicAdd(a + 0, v.x); atomicAdd(a + 1, v.y);
        atomicAdd(a + 2, v.z); atomicAdd(a + 3, v.w);
        if (j == 0) atomicAdd(deg + dst, 1.0f);
    }
}
__global__ __launch_bounds__(1024) void sage_scalar(
        const float* __restrict__ x, const float* __restrict__ agg_in,
        const float* __restrict__ deg,
        const float* __restrict__ Wl, const float* __restrict__ bl,
        const float* __restrict__ Wr,
        const float* __restrict__ gamma, const float* __restrict__ beta,
        float* __restrict__ out, int n_nodes) {
    __shared__ float wlt[128 * 129];
    __shared__ float wrt[128 * 129];
    __shared__ float rows[16][256];
    int tid = threadIdx.x;
    for (int i = tid; i < 128 * 128; i += 1024) {
        int d = i >> 7, k = i & 127;
        wlt[k * 129 + d] = Wl[i];
        wrt[k * 129 + d] = Wr[i];
    }
    __syncthreads();
    int wave = tid >> 6, lane = tid & 63;
    int gwave = blockIdx.x * 16 + wave;
    int nwaves = gridDim.x * 16;
    float* row = rows[wave];
    int d0 = lane, d1 = lane + 64;
    float bl0 = bl[d0], bl1 = bl[d1];
    float g0 = gamma[d0], g1 = gamma[d1];
    float be0 = beta[d0], be1 = beta[d1];
    for (int n = gwave; n < n_nodes; n += nwaves) {
        float inv = 1.0f / fmaxf(deg[n], 1.0f);
        long long base = (long long)n * D;
        row[lane]       = agg_in[base + lane] * inv;
        row[lane + 64]  = agg_in[base + lane + 64] * inv;
        row[lane + 128] = x[base + lane];
        row[lane + 192] = x[base + lane + 64];
        float acc0 = bl0, acc1 = bl1;
        #pragma unroll 4
        for (int k = 0; k < 128; ++k) {
            float a  = row[k];
            float xv = row[128 + k];
            acc0 += a * wlt[k * 129 + d0];
            acc1 += a * wlt[k * 129 + d1];
            acc0 += xv * wrt[k * 129 + d0];
            acc1 += xv * wrt[k * 129 + d1];
        }
        float s  = acc0 + acc1;
        float sq = acc0 * acc0 + acc1 * acc1;
        #pragma unroll
        for (int off = 32; off >= 1; off >>= 1) {
            s  += __shfl_xor(s, off, 64);
            sq += __shfl_xor(sq, off, 64);
        }
        float mu = s * (1.0f / 128.0f);
        float var = sq * (1.0f / 128.0f) - mu * mu;
        float rstd = rsqrtf(var + 1e-5f);
        float o0 = (acc0 - mu) * rstd * g0 + be0;
        float o1 = (acc1 - mu) * rstd * g1 + be1;
        out[base + d0] = fmaxf(o0, 0.0f);
        out[base + d1] = fmaxf(o1, 0.0f);
    }
}

extern "C" void kernel_launch(void* const* d_in, const int* in_sizes, int n_in,
                              void* d_out, int out_size, void* d_ws, size_t ws_size,
                              hipStream_t stream) {
    const float* x     = (const float*)d_in[0];
    const int*   ei    = (const int*)d_in[1];
    const float* Wl    = (const float*)d_in[2];
    const float* bl    = (const float*)d_in[3];
    const float* Wr    = (const float*)d_in[4];
    const float* gamma = (const float*)d_in[5];
    const float* beta  = (const float*)d_in[6];

    int n_nodes = in_sizes[0] / D;
    int n_edges = in_sizes[1] / 2;
    int nb = (n_nodes + NPB - 1) / NPB;

    // ws layout (ints): deg[N] | offs[N+1] | cursor[N] | bsum[256] | boff[256]
    //                   | bc[MAXNB] | bbase[MAXNB+1] | bcur[MAXNB] | csr[E]
    //                   | [256-aligned] agg_bf16[N*128] | xb_bf16[N*128]
    // staged (E u32) aliases the agg region (dead before gather writes agg).
    size_t int_elems = (size_t)n_nodes * 3 + 1 + 2 * SCAN_NB + (3 * MAXNB + 1) + (size_t)n_edges;
    size_t int_bytes = int_elems * sizeof(int);
    size_t aggb_off  = (int_bytes + 255) & ~(size_t)255;
    size_t xb_off    = aggb_off + (size_t)n_nodes * 128 * 2;
    size_t need_full = xb_off + (size_t)n_nodes * 128 * 2;
    size_t need_a    = xb_off;
    size_t need_b    = int_bytes;

    if (ws_size >= need_b) {
        int* deg    = (int*)d_ws;
        int* offs   = deg + n_nodes;
        int* cursor = offs + n_nodes + 1;
        int* bsum   = cursor + n_nodes;
        int* boff   = bsum + SCAN_NB;
        int* bc     = boff + SCAN_NB;
        int* bbase  = bc + MAXNB;
        int* bcur   = bbase + MAXNB + 1;
        int* csr    = bcur + MAXNB;

        bool binnable = (nb <= MAXNB) && (n_nodes < (1 << 24)) &&
                        ((size_t)n_edges * 4 <= (size_t)n_nodes * 128 * 2);

        if (ws_size >= need_full && binnable) {
            void* aggb = (char*)d_ws + aggb_off;
            unsigned int* xb = (unsigned int*)((char*)d_ws + xb_off);
            unsigned int* staged = (unsigned int*)aggb;   // alias: dead before gather

            hipMemsetAsync(bc, 0, (size_t)nb * sizeof(int), stream);
            convert_kernel<<<2048, 256, 0, stream>>>(x, xb, (long long)n_nodes * 32);
            bucket_count<<<256, 256, 0, stream>>>(ei, bc, n_edges, nb);
            bucket_scan<<<1, 1024, 0, stream>>>(bc, bbase, bcur, offs, nb, n_nodes);
            bin_kernel<<<256, 256, 0, stream>>>(ei, bcur, staged, n_edges, nb);
            fill2_sort<<<nb, 256, 0, stream>>>(staged, bbase, offs, csr, n_nodes);
            gather4_kernel<<<2048, 256, 0, stream>>>(xb, offs, csr, (unsigned int*)aggb,
                                                     n_nodes);
            sage_mfma<1, 1><<<512, 256, 0, stream>>>(xb, aggb, Wl, bl, Wr, gamma, beta,
                                                     (float*)d_out, n_nodes);
        } else {
            // legacy CSR build
            hipMemsetAsync(deg, 0, (size_t)n_nodes * sizeof(int), stream);
            count_kernel<<<2048, 256, 0, stream>>>(ei, deg, n_edges);
            scan_partA<<<SCAN_NB, 256, 0, stream>>>(deg, bsum, n_nodes);
            scan_partB<<<1, SCAN_NB, 0, stream>>>(bsum, boff, offs, n_nodes);
            scan_partC<<<SCAN_NB, 256, 0, stream>>>(deg, boff, offs, cursor, n_nodes);
            fill_kernel<<<2048, 256, 0, stream>>>(ei, cursor, csr, n_edges);

            if (ws_size >= need_full) {
                void* aggb = (char*)d_ws + aggb_off;
                unsigned int* xb = (unsigned int*)((char*)d_ws + xb_off);
                convert_kernel<<<2048, 256, 0, stream>>>(x, xb, (long long)n_nodes * 32);
                gather4_kernel<<<2048, 256, 0, stream>>>(xb, offs, csr,
                                                         (unsigned int*)aggb, n_nodes);
                sage_mfma<1, 1><<<512, 256, 0, stream>>>(xb, aggb, Wl, bl, Wr, gamma,
                                                         beta, (float*)d_out, n_nodes);
            } else if (ws_size >= need_a) {
                void* aggb = (char*)d_ws + aggb_off;
                gather_kernel<0, 1><<<2048, 256, 0, stream>>>(x, offs, csr, aggb, n_nodes);
                sage_mfma<1, 0><<<512, 256, 0, stream>>>(x, aggb, Wl, bl, Wr, gamma, beta,
                                                         (float*)d_out, n_nodes);
            } else {
                float* aggf = (float*)d_out;
                gather_kernel<0, 0><<<2048, 256, 0, stream>>>(x, offs, csr, aggf, n_nodes);
                sage_mfma<0, 0><<<512, 256, 0, stream>>>(x, aggf, Wl, bl, Wr, gamma, beta,
                                                         (float*)d_out, n_nodes);
            }
        }
    } else {
        float* degf = (float*)d_ws;
        zero_f<<<2048, 256, 0, stream>>>((float*)d_out, degf, n_nodes);
        scatter_kernel<<<2048, 256, 0, stream>>>(x, ei, (float*)d_out, degf, n_edges);
        sage_scalar<<<512, 1024, 0, stream>>>(x, (float*)d_out, degf, Wl, bl, Wr,
                                              gamma, beta, (float*)d_out, n_nodes);
    }
}